// Round 12
// baseline (465.731 us; speedup 1.0000x reference)
//
#include <hip/hip_runtime.h>
#include <hip/hip_bf16.h>
#include <hip/hip_fp16.h>
#include <cstdint>

#define F_IN 128
#define F_HID 64
#define NB 64          // nodes per bucket
#define MAXB 2048      // max buckets (N <= 131072)
#define NWG 256        // WGs for hist/fill edge partition
#define PREPB 16       // prep blocks inside k_front
#define STAGE 12800    // k_bfill LDS staging capacity (records per sub-chunk)

typedef _Float16 half8 __attribute__((ext_vector_type(8)));
typedef float floatx4 __attribute__((ext_vector_type(4)));

__device__ __forceinline__ float bf2f(unsigned short u) {
  return __uint_as_float(((unsigned int)u) << 16);
}
__device__ __forceinline__ unsigned short f2bf(float f) {
  unsigned int u = __float_as_uint(f);
  u += 0x7FFFu + ((u >> 16) & 1u);   // round-to-nearest-even
  return (unsigned short)(u >> 16);
}
__device__ __forceinline__ float h2f(unsigned short u) {
  return __half2float(__ushort_as_half(u));
}
__device__ __forceinline__ unsigned short f2h(float f) {
  return __half_as_ushort(__float2half(f));
}

// ---------------- inline dtype detection (replaces k_detect kernel) ----------------
// Every thread scans X's first 256 words (L2-broadcast, ~few hundred cycles).
// Block-uniform result; removes a serial head-of-graph dispatch.
__device__ __forceinline__ bool detect_bf16(const void* Xv) {
  const unsigned int* Xw = (const unsigned int*)Xv;
  int cnt = 0;
#pragma unroll 8
  for (int t = 0; t < 256; t++) {
    unsigned int ex = (Xw[t] >> 7) & 0xFFu;
    cnt += (ex >= 117u && ex <= 137u) ? 1 : 0;
  }
  return cnt >= 128;  // 1 = bf16, 0 = fp32
}

// ---------------- fused front: bhist | weight-prep | xcast (independent) ----------------
// blocks [0,NWG): edge histogram; [NWG,NWG+PREPB): weight prep; rest: X cast.
__global__ __launch_bounds__(256) void k_front(const void* __restrict__ Xv,
                                               unsigned short* __restrict__ Xh, int total8,
                                               const void* __restrict__ W1v,
                                               const void* __restrict__ W2v,
                                               const void* __restrict__ fc1Wv,
                                               unsigned short* __restrict__ fW1,
                                               unsigned short* __restrict__ fW2,
                                               unsigned short* __restrict__ fPR,
                                               const int* __restrict__ dst,
                                               int* __restrict__ hist, int E, int B, int chunk) {
  __shared__ int lh[MAXB];
  const int bid = blockIdx.x;
  if (bid < NWG) {  // ---- bhist ----
    int w = bid, tid = threadIdx.x;
    for (int b = tid; b < B; b += 256) lh[b] = 0;
    __syncthreads();
    int e0 = w * chunk, e1 = min(E, e0 + chunk);
    for (int e = e0 + tid; e < e1; e += 256) atomicAdd(&lh[dst[e] >> 6], 1);
    __syncthreads();
    for (int b = tid; b < B; b += 256) hist[w * B + b] = lh[b];
    return;
  }
  const bool isb = detect_bf16(Xv);
  if (bid < NWG + PREPB) {  // ---- weight prep (frag-order fp16) ----
    // B-frag for mfma_f32_16x16x32_f16: B[k=(lane>>4)*8+j][n=lane&15].
    // dest (ushorts) for W element (k,n): c=k>>5,q=(k>>3)&3,j=k&7,t=n>>4,m=n&15
    //   -> ((c*4+t)*64 + q*16+m)*8 + j
    int tid = (bid - NWG) * 256 + threadIdx.x;
    int stride = PREPB * 256;
    for (int e = tid; e < F_IN * F_HID; e += stride) {
      int k = e >> 6, n = e & 63;
      unsigned short v = isb ? f2h(bf2f(((const unsigned short*)W1v)[e]))
                             : f2h(((const float*)W1v)[e]);
      int c = k >> 5, q = (k >> 3) & 3, j = k & 7, t = n >> 4, m = n & 15;
      fW1[((c * 4 + t) * 64 + q * 16 + m) * 8 + j] = v;
    }
    for (int e = tid; e < F_HID * F_HID; e += stride) {
      int k = e >> 6, n = e & 63;
      unsigned short v = isb ? f2h(bf2f(((const unsigned short*)W2v)[e]))
                             : f2h(((const float*)W2v)[e]);
      int c = k >> 5, q = (k >> 3) & 3, j = k & 7, t = n >> 4, m = n & 15;
      fW2[((c * 4 + t) * 64 + q * 16 + m) * 8 + j] = v;
    }
    // fc1_W, 4 groups of 64x64: g&2 row half (Wa/Wb), g&1 col half
    for (int ge = tid; ge < 4 * F_HID * 64; ge += stride) {
      int g = ge >> 12, e = ge & 4095;
      int k = e >> 6, n = e & 63;
      int src = (((g & 2) ? 64 : 0) + k) * 128 + (g & 1) * 64 + n;
      unsigned short v = isb ? f2h(bf2f(((const unsigned short*)fc1Wv)[src]))
                             : f2h(((const float*)fc1Wv)[src]);
      int c = k >> 5, q = (k >> 3) & 3, j = k & 7, t = n >> 4, m = n & 15;
      fPR[g * 4096 + ((c * 4 + t) * 64 + q * 16 + m) * 8 + j] = v;
    }
    return;
  }
  // ---- xcast: lane-linear streaming bf16/fp32 -> fp16 ----
  int t = (bid - (NWG + PREPB)) * 256 + threadIdx.x;
  int stride = (gridDim.x - (NWG + PREPB)) * 256;
  for (; t < total8; t += stride) {
    unsigned short r[8];
    if (isb) {
      uint4 d = reinterpret_cast<const uint4*>(Xv)[t];  // 8 bf16
      r[0] = f2h(__uint_as_float(d.x << 16));
      r[1] = f2h(__uint_as_float(d.x & 0xFFFF0000u));
      r[2] = f2h(__uint_as_float(d.y << 16));
      r[3] = f2h(__uint_as_float(d.y & 0xFFFF0000u));
      r[4] = f2h(__uint_as_float(d.z << 16));
      r[5] = f2h(__uint_as_float(d.z & 0xFFFF0000u));
      r[6] = f2h(__uint_as_float(d.w << 16));
      r[7] = f2h(__uint_as_float(d.w & 0xFFFF0000u));
    } else {
      float4 a = reinterpret_cast<const float4*>(Xv)[2 * t];
      float4 b = reinterpret_cast<const float4*>(Xv)[2 * t + 1];
      r[0] = f2h(a.x); r[1] = f2h(a.y); r[2] = f2h(a.z); r[3] = f2h(a.w);
      r[4] = f2h(b.x); r[5] = f2h(b.y); r[6] = f2h(b.z); r[7] = f2h(b.w);
    }
    uint4 o;
    o.x = (unsigned int)r[0] | ((unsigned int)r[1] << 16);
    o.y = (unsigned int)r[2] | ((unsigned int)r[3] << 16);
    o.z = (unsigned int)r[4] | ((unsigned int)r[5] << 16);
    o.w = (unsigned int)r[6] | ((unsigned int)r[7] << 16);
    reinterpret_cast<uint4*>(Xh)[t] = o;
  }
}

// ---------------- bscan1: wave-per-bucket parallel scan over W=NWG ----------------
__global__ __launch_bounds__(256) void k_bscan1(int* __restrict__ hist,
                                                int* __restrict__ btot, int B) {
  const int WPL = NWG / 64;  // hist entries per lane
  int b = (blockIdx.x * 256 + threadIdx.x) >> 6;  // bucket = global wave id
  int lane = threadIdx.x & 63;
  if (b >= B) return;
  int v[WPL];
  int s = 0;
#pragma unroll
  for (int k = 0; k < WPL; k++) {
    v[k] = hist[(size_t)(lane * WPL + k) * B + b];
    s += v[k];
  }
  // inclusive scan of s across 64 lanes -> exclusive prefix
  int pre = s;
#pragma unroll
  for (int off = 1; off < 64; off <<= 1) {
    int t = __shfl_up(pre, off, 64);
    if (lane >= off) pre += t;
  }
  int running = pre - s;  // exclusive
#pragma unroll
  for (int k = 0; k < WPL; k++) {
    int val = v[k];
    hist[(size_t)(lane * WPL + k) * B + b] = running;
    running += val;
  }
  if (lane == 63) btot[b] = running;  // bucket total
}

// ---------------- bfill: LDS-staged counting sort + fused bucket-base scan ----------------
// bscan2 fused: each block computes boff locally from btot (cheap redundant
// LDS scan); block 0 publishes global boff for k_bsort. LDS-staged binning
// (round-11): write p-linearly so consecutive lanes write consecutive buck[]
// slots. record = (dst_local << 17) | src (needs N <= 131072).
__global__ __launch_bounds__(256) void k_bfill(const int* __restrict__ src,
                                               const int* __restrict__ dst,
                                               const int* __restrict__ hist,
                                               const int* __restrict__ btot,
                                               int* __restrict__ boff,
                                               int* __restrict__ buck,
                                               int E, int B, int chunk) {
  __shared__ int gcur[MAXB];                 // global write base per bucket
  __shared__ int lexcl[MAXB];                // local excl offsets (temp: boff)
  __shared__ int lcur[MAXB];                 // placement cursors
  __shared__ int stage[STAGE];               // bucket-sorted records
  __shared__ unsigned short bdex[STAGE];     // bucket id per staged slot
  __shared__ int part[256];
  const int w = blockIdx.x, tid = threadIdx.x;
  // ---- fused bscan2: local exclusive scan of btot -> bucket bases ----
  {
    int CH = (B + 255) >> 8;
    int b0 = tid * CH, b1 = min(B, b0 + CH);
    int s = 0;
    for (int b = b0; b < b1; b++) s += btot[b];
    part[tid] = s;
    __syncthreads();
    if (tid == 0) {
      int acc = 0;
      for (int i = 0; i < 256; i++) { int v = part[i]; part[i] = acc; acc += v; }
    }
    __syncthreads();
    int run = part[tid];
    for (int b = b0; b < b1; b++) { lexcl[b] = run; run += btot[b]; }
    __syncthreads();
    for (int b = tid; b < B; b += 256) gcur[b] = lexcl[b] + hist[w * B + b];
    if (w == 0) {  // publish for k_bsort
      for (int b = tid; b < B; b += 256) boff[b] = lexcl[b];
      if (tid == 0) boff[B] = E;
    }
    __syncthreads();  // lexcl free for reuse below
  }
  int e0 = w * chunk, e1 = min(E, e0 + chunk);
  for (int s0 = e0; s0 < e1; s0 += STAGE) {
    int s1 = min(e1, s0 + STAGE);
    int cnt = s1 - s0;
    for (int b = tid; b < B; b += 256) lexcl[b] = 0;
    __syncthreads();
    for (int e = s0 + tid; e < s1; e += 256) atomicAdd(&lexcl[dst[e] >> 6], 1);
    __syncthreads();
    // block exclusive scan of lexcl; init lcur
    int CH = (B + 255) >> 8;
    int b0 = tid * CH, b1 = min(B, b0 + CH);
    int s = 0;
    for (int b = b0; b < b1; b++) s += lexcl[b];
    part[tid] = s;
    __syncthreads();
    if (tid == 0) {
      int acc = 0;
      for (int i = 0; i < 256; i++) { int v = part[i]; part[i] = acc; acc += v; }
    }
    __syncthreads();
    int run = part[tid];
    for (int b = b0; b < b1; b++) {
      int v = lexcl[b];
      lexcl[b] = run;
      lcur[b] = run;
      run += v;
    }
    __syncthreads();
    // place records bucket-sorted into stage
    for (int e = s0 + tid; e < s1; e += 256) {
      int d = dst[e];
      int b = d >> 6;
      int p = atomicAdd(&lcur[b], 1);
      stage[p] = ((d & 63) << 17) | src[e];
      bdex[p] = (unsigned short)b;
    }
    __syncthreads();
    // p-linear write-out: consecutive p -> consecutive dest within runs
    for (int p = tid; p < cnt; p += 256) {
      int b = bdex[p];
      buck[gcur[b] + (p - lexcl[b])] = stage[p];
    }
    __syncthreads();
    // advance global bases by this sub-chunk's per-bucket counts
    for (int b = tid; b < B; b += 256) gcur[b] += lcur[b] - lexcl[b];
    __syncthreads();
  }
}

// ---------------- per-bucket counting sort -> exact per-node CSR ----------------
// 8-way replicated counters/cursors (bin[dl][rep], rep = tid&7): halves the
// residual same-address LDS atomic serialization vs 4-way. Slot order within
// a node's segment changes — permutation-invariant downstream.
__global__ __launch_bounds__(256) void k_bsort(const int* __restrict__ buck,
                                               const int* __restrict__ boff,
                                               int* __restrict__ csr,
                                               int* __restrict__ noff,
                                               float* __restrict__ dinv, int N) {
  __shared__ int bin[NB][8];
  __shared__ int excl[NB];
  int b = blockIdx.x, tid = threadIdx.x;
  const int rep = tid & 7;
  for (int i = tid; i < NB * 8; i += 256) ((int*)bin)[i] = 0;
  __syncthreads();
  int r0 = boff[b], r1 = boff[b + 1];
  for (int r = r0 + tid; r < r1; r += 256) atomicAdd(&bin[buck[r] >> 17][rep], 1);
  __syncthreads();
  if (tid < NB) {
    int t = 0;
#pragma unroll
    for (int r = 0; r < 8; r++) t += bin[tid][r];
    excl[tid] = t;
  }
  __syncthreads();
  if (tid == 0) {
    int acc = 0;
    for (int i = 0; i < NB; i++) { int v = excl[i]; excl[i] = acc; acc += v; }
  }
  __syncthreads();
  if (tid < NB) {
    int n = b * NB + tid;
    int tot = 0;
#pragma unroll
    for (int r = 0; r < 8; r++) tot += bin[tid][r];
    if (n < N) {
      dinv[n] = rsqrtf((float)tot + 1.0f);  // +1 self-loop
      noff[n] = r0 + excl[tid];
    }
    // replica cursors: disjoint sub-ranges of this node's segment
    int acc = excl[tid];
#pragma unroll
    for (int r = 0; r < 8; r++) { int c = bin[tid][r]; bin[tid][r] = acc; acc += c; }
  }
  if (b == gridDim.x - 1 && tid == 128) noff[N] = r1;  // r1 == E for last bucket
  __syncthreads();
  for (int r = r0 + tid; r < r1; r += 256) {
    int rec = buck[r];
    int p = atomicAdd(&bin[rec >> 17][rep], 1);
    csr[r0 + p] = rec & 0x1FFFF;
  }
}

// ============ MFMA GEMMs (mfma_f32_16x16x32_f16), all inputs fp16 ============
// A-frag:  A[m = lane&15][k = (lane>>4)*8 + j]
// D:       D[row = (lane>>4)*4 + reg][col = lane&15]

// ---------------- GEMM1: G = fp16((Xh @ W1) * dinv[row])   (Xh fp16 N x 128) ----------------
__global__ __launch_bounds__(256, 4) void k_gemm1(const unsigned short* __restrict__ Xh,
                                                  const unsigned short* __restrict__ fW1,
                                                  const float* __restrict__ dinv,
                                                  unsigned short* __restrict__ G, int N) {
  int tid = threadIdx.x;
  const int lane = tid & 63, wave = tid >> 6;
  const int m = lane & 15, q = lane >> 4;
  half8 bfrag[4][4];
#pragma unroll
  for (int c = 0; c < 4; c++)
#pragma unroll
    for (int t = 0; t < 4; t++)
      bfrag[c][t] = *reinterpret_cast<const half8*>(fW1 + ((c * 4 + t) * 64 + lane) * 8);
  int ntiles = (N + 15) >> 4;
  for (int tile = blockIdx.x * 4 + wave; tile < ntiles; tile += gridDim.x * 4) {
    int r0 = tile << 4;
    int rm = r0 + m; rm = rm < N ? rm : N - 1;
    floatx4 acc[4] = {{0.f,0.f,0.f,0.f},{0.f,0.f,0.f,0.f},{0.f,0.f,0.f,0.f},{0.f,0.f,0.f,0.f}};
#pragma unroll
    for (int c = 0; c < 4; c++) {
      half8 a = *reinterpret_cast<const half8*>(Xh + (size_t)rm * F_IN + c * 32 + q * 8);
#pragma unroll
      for (int t = 0; t < 4; t++)
        acc[t] = __builtin_amdgcn_mfma_f32_16x16x32_f16(a, bfrag[c][t], acc[t], 0, 0, 0);
    }
#pragma unroll
    for (int rr = 0; rr < 4; rr++) {
      int grow = r0 + q * 4 + rr;
      if (grow < N) {
        float dv = dinv[grow];
#pragma unroll
        for (int t = 0; t < 4; t++)
          G[(size_t)grow * F_HID + t * 16 + m] = f2h(acc[t][rr] * dv);
      }
    }
  }
}

// ---------------- GEMM2: G = fp16((O @ W2) * dinv[row])   (O fp16) ----------------
__global__ __launch_bounds__(256, 4) void k_gemm2(const unsigned short* __restrict__ O,
                                                  const unsigned short* __restrict__ fW2,
                                                  const float* __restrict__ dinv,
                                                  unsigned short* __restrict__ G, int N) {
  int tid = threadIdx.x;
  const int lane = tid & 63, wave = tid >> 6;
  const int m = lane & 15, q = lane >> 4;
  half8 bfrag[2][4];
#pragma unroll
  for (int c = 0; c < 2; c++)
#pragma unroll
    for (int t = 0; t < 4; t++)
      bfrag[c][t] = *reinterpret_cast<const half8*>(fW2 + ((c * 4 + t) * 64 + lane) * 8);
  int ntiles = (N + 15) >> 4;
  for (int tile = blockIdx.x * 4 + wave; tile < ntiles; tile += gridDim.x * 4) {
    int r0 = tile << 4;
    int rm = r0 + m; rm = rm < N ? rm : N - 1;
    floatx4 acc[4] = {{0.f,0.f,0.f,0.f},{0.f,0.f,0.f,0.f},{0.f,0.f,0.f,0.f},{0.f,0.f,0.f,0.f}};
#pragma unroll
    for (int c = 0; c < 2; c++) {
      half8 a = *reinterpret_cast<const half8*>(O + (size_t)rm * F_HID + c * 32 + q * 8);
#pragma unroll
      for (int t = 0; t < 4; t++)
        acc[t] = __builtin_amdgcn_mfma_f32_16x16x32_f16(a, bfrag[c][t], acc[t], 0, 0, 0);
    }
#pragma unroll
    for (int rr = 0; rr < 4; rr++) {
      int grow = r0 + q * 4 + rr;
      if (grow < N) {
        float dv = dinv[grow];
#pragma unroll
        for (int t = 0; t < 4; t++)
          G[(size_t)grow * F_HID + t * 16 + m] = f2h(acc[t][rr] * dv);
      }
    }
  }
}

// ---------------- aggregate: 4 rows/instruction group-gather + fused epilogue ----------------
template <bool RELU>
__global__ __launch_bounds__(256) void k_agg(const int* __restrict__ csr,
                                             const int* __restrict__ noff,
                                             const unsigned short* __restrict__ H,
                                             const float* __restrict__ dinv,
                                             const void* __restrict__ bias,
                                             unsigned short* __restrict__ OUT, int N,
                                             const void* __restrict__ Xv) {
  const bool isb = detect_bf16(Xv);
  const int lane = threadIdx.x & 63;
  const int g = lane >> 4, l16 = lane & 15;
  const int gw = (blockIdx.x * 256 + threadIdx.x) >> 6;
  const int nW = (gridDim.x * 256) >> 6;
  float bv[4];
#pragma unroll
  for (int d = 0; d < 4; d++)
    bv[d] = isb ? bf2f(((const unsigned short*)bias)[l16 * 4 + d])
                : ((const float*)bias)[l16 * 4 + d];
  for (int n = gw; n < N; n += nW) {
    int start = noff[n], end = noff[n + 1];
    float a0 = 0.f, a1 = 0.f, a2 = 0.f, a3 = 0.f;
    for (int e0 = start; e0 < end; e0 += 64) {
      int ee = e0 + lane;
      int idx = (ee < end) ? csr[ee] : 0;
      int m = end - e0; m = m < 64 ? m : 64;
      int nc = m >> 2;  // full 4-row chunks
      int c = 0;
      for (; c + 8 <= nc; c += 8) {  // 32 rows in flight
        int s[8];
#pragma unroll
        for (int u = 0; u < 8; u++) s[u] = __shfl(idx, (c + u) * 4 + g, 64);
        ushort4 v[8];
#pragma unroll
        for (int u = 0; u < 8; u++)
          v[u] = *reinterpret_cast<const ushort4*>(H + (size_t)s[u] * F_HID + l16 * 4);
#pragma unroll
        for (int u = 0; u < 8; u++) {
          a0 += h2f(v[u].x); a1 += h2f(v[u].y);
          a2 += h2f(v[u].z); a3 += h2f(v[u].w);
        }
      }
      for (; c < nc; c++) {
        int s0 = __shfl(idx, c * 4 + g, 64);
        ushort4 v0 = *reinterpret_cast<const ushort4*>(H + (size_t)s0 * F_HID + l16 * 4);
        a0 += h2f(v0.x); a1 += h2f(v0.y); a2 += h2f(v0.z); a3 += h2f(v0.w);
      }
      int rem = m & 3;
      if (rem) {
        int s0 = __shfl(idx, nc * 4 + g, 64);  // shfl outside divergence
        if (g < rem) {
          ushort4 v0 = *reinterpret_cast<const ushort4*>(H + (size_t)s0 * F_HID + l16 * 4);
          a0 += h2f(v0.x); a1 += h2f(v0.y); a2 += h2f(v0.z); a3 += h2f(v0.w);
        }
      }
    }
    // cross-group reduce (butterfly: all lanes end with totals)
    a0 += __shfl_xor(a0, 16, 64); a0 += __shfl_xor(a0, 32, 64);
    a1 += __shfl_xor(a1, 16, 64); a1 += __shfl_xor(a1, 32, 64);
    a2 += __shfl_xor(a2, 16, 64); a2 += __shfl_xor(a2, 32, 64);
    a3 += __shfl_xor(a3, 16, 64); a3 += __shfl_xor(a3, 32, 64);
    // self-loop + scale + bias (+relu), vector store by lanes 0-15
    ushort4 sv = *reinterpret_cast<const ushort4*>(H + (size_t)n * F_HID + l16 * 4);
    float dv = dinv[n];
    float o0 = (a0 + h2f(sv.x)) * dv + bv[0];
    float o1 = (a1 + h2f(sv.y)) * dv + bv[1];
    float o2 = (a2 + h2f(sv.z)) * dv + bv[2];
    float o3 = (a3 + h2f(sv.w)) * dv + bv[3];
    if (RELU) {
      o0 = fmaxf(o0, 0.f); o1 = fmaxf(o1, 0.f);
      o2 = fmaxf(o2, 0.f); o3 = fmaxf(o3, 0.f);
    }
    if (lane < 16) {
      ushort4 ov;
      ov.x = f2h(o0); ov.y = f2h(o1); ov.z = f2h(o2); ov.w = f2h(o3);
      *reinterpret_cast<ushort4*>(OUT + (size_t)n * F_HID + l16 * 4) = ov;
    }
  }
}

// ---------------- query: gather O[i], O[j]; on-the-fly MFMA MLP ----------------
// out[q] = relu(O[i]@Wa + O[j]@Wb + fc1_b) @ fc2_W + fc2_b
// 512-thread blocks (8 waves share the 32 KB weight copy), depth-1 pipelined
// gathers, sched_barrier acc-halving, setprio around MFMA. ~71 us — pinned at
// the L2/L3 random-line service rate (rounds 8-10 all plateau here).
__global__ __launch_bounds__(512) void k_query(const unsigned short* __restrict__ O,
                                               const unsigned short* __restrict__ fPR,
                                               const int* __restrict__ qi,
                                               const int* __restrict__ qj,
                                               const void* __restrict__ fc1b,
                                               const void* __restrict__ fc2W,
                                               const void* __restrict__ fc2b,
                                               void* __restrict__ out, int Q,
                                               const void* __restrict__ Xv) {
  __shared__ unsigned short sB[4 * 4096];  // 32 KB: fc1_W frag-order
  const bool isb = detect_bf16(Xv);
  int tid = threadIdx.x;
  {
    const uint4* srcp = reinterpret_cast<const uint4*>(fPR);
    uint4* dstp = reinterpret_cast<uint4*>(sB);
#pragma unroll
    for (int r = 0; r < 4; r++) dstp[tid + r * 512] = srcp[tid + r * 512];
  }
  const int lane = tid & 63, wave = tid >> 6;  // wave in [0,8)
  const int m_ = lane & 15, qk = lane >> 4;
  // per-lane epilogue LUT for hid cols h = T*16 + m_
  float bb[8], w0[8], w1[8];
#pragma unroll
  for (int T = 0; T < 8; T++) {
    int h = T * 16 + m_;
    if (isb) {
      bb[T] = bf2f(((const unsigned short*)fc1b)[h]);
      w0[T] = bf2f(((const unsigned short*)fc2W)[h * 2 + 0]);
      w1[T] = bf2f(((const unsigned short*)fc2W)[h * 2 + 1]);
    } else {
      bb[T] = ((const float*)fc1b)[h];
      w0[T] = ((const float*)fc2W)[h * 2 + 0];
      w1[T] = ((const float*)fc2W)[h * 2 + 1];
    }
  }
  float ob0 = isb ? bf2f(((const unsigned short*)fc2b)[0]) : ((const float*)fc2b)[0];
  float ob1 = isb ? bf2f(((const unsigned short*)fc2b)[1]) : ((const float*)fc2b)[1];
  __syncthreads();
  const half8* sBv = reinterpret_cast<const half8*>(sB);  // group stride 512 half8

  const int ntiles = (Q + 15) >> 4;
  const int nW = gridDim.x * 8;
  int tile = blockIdx.x * 8 + wave;
  if (tile >= ntiles) return;

  auto ldidx = [&](int t, int& iq, int& jq) {
    if (t < ntiles) {
      int q = t * 16 + m_;
      int qq = q < Q ? q : Q - 1;
      iq = qi[qq];
      jq = qj[qq];
    }  // else keep previous (harmless row re-gather)
  };
  auto gather = [&](int iq, int jq, half8& I0, half8& I1, half8& J0, half8& J1) {
    const half8* pI = reinterpret_cast<const half8*>(O + (size_t)iq * F_HID) + qk;
    const half8* pJ = reinterpret_cast<const half8*>(O + (size_t)jq * F_HID) + qk;
    I0 = pI[0]; I1 = pI[4];  // k 0-31 / 32-63
    J0 = pJ[0]; J1 = pJ[4];
  };

  // pipeline prologue: idx(t), rows(t), idx(t+1)
  int iqn = 0, jqn = 0;
  ldidx(tile, iqn, jqn);
  half8 I0, I1, J0, J1;
  gather(iqn, jqn, I0, I1, J0, J1);
  ldidx(tile + nW, iqn, jqn);

  for (; tile < ntiles; tile += nW) {
    // issue NEXT tile's row gathers + the tile after's index loads first;
    // they drain while we compute the current tile.
    half8 nI0, nI1, nJ0, nJ1;
    gather(iqn, jqn, nI0, nI1, nJ0, nJ1);
    ldidx(tile + 2 * nW, iqn, jqn);

    float r0[4] = {0.f, 0.f, 0.f, 0.f};
    float r1[4] = {0.f, 0.f, 0.f, 0.f};
    const floatx4 zz = {0.f, 0.f, 0.f, 0.f};
#pragma unroll
    for (int h = 0; h < 2; h++) {  // hid col half: groups {h (Wa), 2+h (Wb)}
      floatx4 acc[4];
#pragma unroll
      for (int tt = 0; tt < 4; tt++) acc[tt] = zz;
      __builtin_amdgcn_s_setprio(1);
#pragma unroll
      for (int tt = 0; tt < 4; tt++) {
        acc[tt] = __builtin_amdgcn_mfma_f32_16x16x32_f16(
            I0, sBv[h * 512 + tt * 64 + lane], acc[tt], 0, 0, 0);
        acc[tt] = __builtin_amdgcn_mfma_f32_16x16x32_f16(
            I1, sBv[h * 512 + (4 + tt) * 64 + lane], acc[tt], 0, 0, 0);
        acc[tt] = __builtin_amdgcn_mfma_f32_16x16x32_f16(
            J0, sBv[(2 + h) * 512 + tt * 64 + lane], acc[tt], 0, 0, 0);
        acc[tt] = __builtin_amdgcn_mfma_f32_16x16x32_f16(
            J1, sBv[(2 + h) * 512 + (4 + tt) * 64 + lane], acc[tt], 0, 0, 0);
      }
      __builtin_amdgcn_s_setprio(0);
      // partial epilogue for this half: fold into persistent r0/r1
#pragma unroll
      for (int tt = 0; tt < 4; tt++) {
        int T = h * 4 + tt;  // hid col = T*16 + m_
#pragma unroll
        for (int rr = 0; rr < 4; rr++) {
          float hv = fmaxf(acc[tt][rr] + bb[T], 0.f);
          r0[rr] += hv * w0[T];
          r1[rr] += hv * w1[T];
        }
      }
      // pin half-1's MFMAs after half-0's fold: halves acc liveness (16 AGPR)
      __builtin_amdgcn_sched_barrier(0);
    }
    // reduce across the 16 lanes of each q-group and store
#pragma unroll
    for (int rr = 0; rr < 4; rr++) {
      float a0 = r0[rr], a1 = r1[rr];
#pragma unroll
      for (int off = 8; off > 0; off >>= 1) {
        a0 += __shfl_xor(a0, off, 16);
        a1 += __shfl_xor(a1, off, 16);
      }
      if (m_ == 0) {
        int q = tile * 16 + qk * 4 + rr;
        if (q < Q) {
          if (isb) {
            *reinterpret_cast<ushort2*>((unsigned short*)out + (size_t)q * 2) =
                make_ushort2(f2bf(a0 + ob0), f2bf(a1 + ob1));
          } else {
            *reinterpret_cast<float2*>((float*)out + (size_t)q * 2) =
                make_float2(a0 + ob0, a1 + ob1);
          }
        }
      }
    }
    // rotate pipeline buffers
    I0 = nI0; I1 = nI1; J0 = nJ0; J1 = nJ1;
  }
}

extern "C" void kernel_launch(void* const* d_in, const int* in_sizes, int n_in,
                              void* d_out, int out_size, void* d_ws, size_t ws_size,
                              hipStream_t stream) {
  const void* X    = d_in[0];
  const int*  edges= (const int*)d_in[1];
  const int*  qi   = (const int*)d_in[2];
  const int*  qj   = (const int*)d_in[3];
  const void* W1   = d_in[4];
  const void* b1   = d_in[5];
  const void* W2   = d_in[6];
  const void* b2   = d_in[7];
  const void* fc1W = d_in[8];
  const void* fc1b = d_in[9];
  const void* fc2W = d_in[10];
  const void* fc2b = d_in[11];

  const int N = in_sizes[0] / F_IN;
  const int E = in_sizes[1] / 2;
  const int Q = in_sizes[2];
  const int B = (N + NB - 1) / NB;           // buckets (<= MAXB for N <= 131072)
  const int chunk = (E + NWG - 1) / NWG;

  char* ws = (char*)d_ws;
  size_t off = 0;
  auto alloc = [&](size_t bytes) -> void* {
    void* p = ws + off;
    off += (bytes + 255) & ~(size_t)255;
    return p;
  };
  float*          dinv = (float*)alloc((size_t)N * 4);
  unsigned short* Xh   = (unsigned short*)alloc((size_t)N * F_IN * 2);   // fp16 X
  unsigned short* G    = (unsigned short*)alloc((size_t)N * F_HID * 2);  // gemm out (fp16)
  unsigned short* O    = (unsigned short*)alloc((size_t)N * F_HID * 2);  // layer out (fp16)
  unsigned short* fW1  = (unsigned short*)alloc((size_t)F_IN * F_HID * 2);   // frag-order fp16
  unsigned short* fW2  = (unsigned short*)alloc((size_t)F_HID * F_HID * 2);
  unsigned short* fPR  = (unsigned short*)alloc((size_t)4 * F_HID * 64 * 2);
  // bucket/CSR scratch
  int* hist = (int*)alloc((size_t)NWG * B * 4);
  int* btot = (int*)alloc((size_t)(B + 1) * 4);
  int* boff = (int*)alloc((size_t)(B + 1) * 4);
  int* buck = (int*)alloc((size_t)E * 4);
  int* csr  = (int*)alloc((size_t)E * 4);
  int* noff = (int*)alloc((size_t)(N + 1) * 4);
  (void)ws_size; (void)n_in; (void)out_size;

  const int* esrc = edges;
  const int* edst = edges + E;

  // fused xcast + weight prep + edge histogram (dtype detect inlined)
  k_front<<<2048, 256, 0, stream>>>(X, Xh, N * F_IN / 8, W1, W2, fc1W, fW1, fW2, fPR,
                                    edst, hist, E, B, chunk);

  // bucket scan + fill (bscan2 fused) + per-bucket counting sort -> CSR/dinv
  k_bscan1<<<(B + 3) / 4, 256, 0, stream>>>(hist, btot, B);
  k_bfill<<<NWG, 256, 0, stream>>>(esrc, edst, hist, btot, boff, buck, E, B, chunk);
  k_bsort<<<B, 256, 0, stream>>>(buck, boff, csr, noff, dinv, N);

  // layer 1
  k_gemm1<<<2048, 256, 0, stream>>>(Xh, fW1, dinv, G, N);
  k_agg<true><<<2048, 256, 0, stream>>>(csr, noff, G, dinv, b1, O, N, X);

  // layer 2
  k_gemm2<<<2048, 256, 0, stream>>>(O, fW2, dinv, G, N);
  k_agg<false><<<2048, 256, 0, stream>>>(csr, noff, G, dinv, b2, O, N, X);

  // per-query: gather O[i], O[j]; MFMA MLP on the fly (512-thread blocks)
  k_query<<<1024, 512, 0, stream>>>(O, fPR, qi, qj, fc1b, fc2W, fc2b, d_out, Q, X);
}

// Round 13
// 436.312 us; speedup vs baseline: 1.0674x; 1.0674x over previous
//
#include <hip/hip_runtime.h>
#include <hip/hip_bf16.h>
#include <hip/hip_fp16.h>
#include <cstdint>

#define F_IN 128
#define F_HID 64
#define NB 64          // nodes per bucket
#define MAXB 2048      // max buckets (N <= 131072)
#define NWG 256        // WGs for hist/fill edge partition
#define PREPB 16       // prep blocks inside k_front
#define STAGE 12800    // k_bfill LDS staging capacity (records per sub-chunk)

typedef _Float16 half8 __attribute__((ext_vector_type(8)));
typedef float floatx4 __attribute__((ext_vector_type(4)));

__device__ __forceinline__ float bf2f(unsigned short u) {
  return __uint_as_float(((unsigned int)u) << 16);
}
__device__ __forceinline__ unsigned short f2bf(float f) {
  unsigned int u = __float_as_uint(f);
  u += 0x7FFFu + ((u >> 16) & 1u);   // round-to-nearest-even
  return (unsigned short)(u >> 16);
}
__device__ __forceinline__ float h2f(unsigned short u) {
  return __half2float(__ushort_as_half(u));
}
__device__ __forceinline__ unsigned short f2h(float f) {
  return __half_as_ushort(__float2half(f));
}

// ---------------- dtype detection kernel (round-12 lesson: do NOT inline —
// per-block redundant 256-word scans cost k_query +10us and k_agg +10us) ----
__global__ __launch_bounds__(64) void k_detect(const unsigned int* __restrict__ Xw,
                                               int* __restrict__ flag) {
  int lane = threadIdx.x;
  int cnt = 0;
  for (int t = lane; t < 256; t += 64) {
    unsigned int ex = (Xw[t] >> 7) & 0xFFu;
    cnt += (ex >= 117u && ex <= 137u) ? 1 : 0;
  }
#pragma unroll
  for (int off = 32; off > 0; off >>= 1) cnt += __shfl_xor(cnt, off, 64);
  if (lane == 0) *flag = (cnt >= 128) ? 1 : 0;  // 1 = bf16, 0 = fp32
}

// ---------------- fused front: bhist | weight-prep | xcast (independent) ----------------
// blocks [0,NWG): edge histogram; [NWG,NWG+PREPB): weight prep; rest: X cast.
__global__ __launch_bounds__(256) void k_front(const void* __restrict__ Xv,
                                               unsigned short* __restrict__ Xh, int total8,
                                               const void* __restrict__ W1v,
                                               const void* __restrict__ W2v,
                                               const void* __restrict__ fc1Wv,
                                               unsigned short* __restrict__ fW1,
                                               unsigned short* __restrict__ fW2,
                                               unsigned short* __restrict__ fPR,
                                               const int* __restrict__ dst,
                                               int* __restrict__ hist, int E, int B, int chunk,
                                               const int* __restrict__ flagp) {
  __shared__ int lh[MAXB];
  const int bid = blockIdx.x;
  if (bid < NWG) {  // ---- bhist ----
    int w = bid, tid = threadIdx.x;
    for (int b = tid; b < B; b += 256) lh[b] = 0;
    __syncthreads();
    int e0 = w * chunk, e1 = min(E, e0 + chunk);
    for (int e = e0 + tid; e < e1; e += 256) atomicAdd(&lh[dst[e] >> 6], 1);
    __syncthreads();
    for (int b = tid; b < B; b += 256) hist[w * B + b] = lh[b];
    return;
  }
  const bool isb = (*flagp != 0);
  if (bid < NWG + PREPB) {  // ---- weight prep (frag-order fp16) ----
    // B-frag for mfma_f32_16x16x32_f16: B[k=(lane>>4)*8+j][n=lane&15].
    // dest (ushorts) for W element (k,n): c=k>>5,q=(k>>3)&3,j=k&7,t=n>>4,m=n&15
    //   -> ((c*4+t)*64 + q*16+m)*8 + j
    int tid = (bid - NWG) * 256 + threadIdx.x;
    int stride = PREPB * 256;
    for (int e = tid; e < F_IN * F_HID; e += stride) {
      int k = e >> 6, n = e & 63;
      unsigned short v = isb ? f2h(bf2f(((const unsigned short*)W1v)[e]))
                             : f2h(((const float*)W1v)[e]);
      int c = k >> 5, q = (k >> 3) & 3, j = k & 7, t = n >> 4, m = n & 15;
      fW1[((c * 4 + t) * 64 + q * 16 + m) * 8 + j] = v;
    }
    for (int e = tid; e < F_HID * F_HID; e += stride) {
      int k = e >> 6, n = e & 63;
      unsigned short v = isb ? f2h(bf2f(((const unsigned short*)W2v)[e]))
                             : f2h(((const float*)W2v)[e]);
      int c = k >> 5, q = (k >> 3) & 3, j = k & 7, t = n >> 4, m = n & 15;
      fW2[((c * 4 + t) * 64 + q * 16 + m) * 8 + j] = v;
    }
    // fc1_W, 4 groups of 64x64: g&2 row half (Wa/Wb), g&1 col half
    for (int ge = tid; ge < 4 * F_HID * 64; ge += stride) {
      int g = ge >> 12, e = ge & 4095;
      int k = e >> 6, n = e & 63;
      int src = (((g & 2) ? 64 : 0) + k) * 128 + (g & 1) * 64 + n;
      unsigned short v = isb ? f2h(bf2f(((const unsigned short*)fc1Wv)[src]))
                             : f2h(((const float*)fc1Wv)[src]);
      int c = k >> 5, q = (k >> 3) & 3, j = k & 7, t = n >> 4, m = n & 15;
      fPR[g * 4096 + ((c * 4 + t) * 64 + q * 16 + m) * 8 + j] = v;
    }
    return;
  }
  // ---- xcast: lane-linear streaming bf16/fp32 -> fp16 ----
  int t = (bid - (NWG + PREPB)) * 256 + threadIdx.x;
  int stride = (gridDim.x - (NWG + PREPB)) * 256;
  for (; t < total8; t += stride) {
    unsigned short r[8];
    if (isb) {
      uint4 d = reinterpret_cast<const uint4*>(Xv)[t];  // 8 bf16
      r[0] = f2h(__uint_as_float(d.x << 16));
      r[1] = f2h(__uint_as_float(d.x & 0xFFFF0000u));
      r[2] = f2h(__uint_as_float(d.y << 16));
      r[3] = f2h(__uint_as_float(d.y & 0xFFFF0000u));
      r[4] = f2h(__uint_as_float(d.z << 16));
      r[5] = f2h(__uint_as_float(d.z & 0xFFFF0000u));
      r[6] = f2h(__uint_as_float(d.w << 16));
      r[7] = f2h(__uint_as_float(d.w & 0xFFFF0000u));
    } else {
      float4 a = reinterpret_cast<const float4*>(Xv)[2 * t];
      float4 b = reinterpret_cast<const float4*>(Xv)[2 * t + 1];
      r[0] = f2h(a.x); r[1] = f2h(a.y); r[2] = f2h(a.z); r[3] = f2h(a.w);
      r[4] = f2h(b.x); r[5] = f2h(b.y); r[6] = f2h(b.z); r[7] = f2h(b.w);
    }
    uint4 o;
    o.x = (unsigned int)r[0] | ((unsigned int)r[1] << 16);
    o.y = (unsigned int)r[2] | ((unsigned int)r[3] << 16);
    o.z = (unsigned int)r[4] | ((unsigned int)r[5] << 16);
    o.w = (unsigned int)r[6] | ((unsigned int)r[7] << 16);
    reinterpret_cast<uint4*>(Xh)[t] = o;
  }
}

// ---------------- bscan1: wave-per-bucket parallel scan over W=NWG ----------------
__global__ __launch_bounds__(256) void k_bscan1(int* __restrict__ hist,
                                                int* __restrict__ btot, int B) {
  const int WPL = NWG / 64;  // hist entries per lane
  int b = (blockIdx.x * 256 + threadIdx.x) >> 6;  // bucket = global wave id
  int lane = threadIdx.x & 63;
  if (b >= B) return;
  int v[WPL];
  int s = 0;
#pragma unroll
  for (int k = 0; k < WPL; k++) {
    v[k] = hist[(size_t)(lane * WPL + k) * B + b];
    s += v[k];
  }
  // inclusive scan of s across 64 lanes -> exclusive prefix
  int pre = s;
#pragma unroll
  for (int off = 1; off < 64; off <<= 1) {
    int t = __shfl_up(pre, off, 64);
    if (lane >= off) pre += t;
  }
  int running = pre - s;  // exclusive
#pragma unroll
  for (int k = 0; k < WPL; k++) {
    int val = v[k];
    hist[(size_t)(lane * WPL + k) * B + b] = running;
    running += val;
  }
  if (lane == 63) btot[b] = running;  // bucket total
}

// ---------------- bfill: LDS-staged counting sort + fused bucket-base scan ----------------
// bscan2 fused: each block computes boff locally from btot (cheap redundant
// LDS scan of B~1563 ints); block 0 publishes global boff for k_bsort.
// LDS-staged binning: write p-linearly so consecutive lanes write consecutive
// buck[] slots. record = (dst_local << 17) | src (needs N <= 131072).
__global__ __launch_bounds__(256) void k_bfill(const int* __restrict__ src,
                                               const int* __restrict__ dst,
                                               const int* __restrict__ hist,
                                               const int* __restrict__ btot,
                                               int* __restrict__ boff,
                                               int* __restrict__ buck,
                                               int E, int B, int chunk) {
  __shared__ int gcur[MAXB];                 // global write base per bucket
  __shared__ int lexcl[MAXB];                // local excl offsets (temp: boff)
  __shared__ int lcur[MAXB];                 // placement cursors
  __shared__ int stage[STAGE];               // bucket-sorted records
  __shared__ unsigned short bdex[STAGE];     // bucket id per staged slot
  __shared__ int part[256];
  const int w = blockIdx.x, tid = threadIdx.x;
  // ---- fused bscan2: local exclusive scan of btot -> bucket bases ----
  {
    int CH = (B + 255) >> 8;
    int b0 = tid * CH, b1 = min(B, b0 + CH);
    int s = 0;
    for (int b = b0; b < b1; b++) s += btot[b];
    part[tid] = s;
    __syncthreads();
    if (tid == 0) {
      int acc = 0;
      for (int i = 0; i < 256; i++) { int v = part[i]; part[i] = acc; acc += v; }
    }
    __syncthreads();
    int run = part[tid];
    for (int b = b0; b < b1; b++) { lexcl[b] = run; run += btot[b]; }
    __syncthreads();
    for (int b = tid; b < B; b += 256) gcur[b] = lexcl[b] + hist[w * B + b];
    if (w == 0) {  // publish for k_bsort
      for (int b = tid; b < B; b += 256) boff[b] = lexcl[b];
      if (tid == 0) boff[B] = E;
    }
    __syncthreads();  // lexcl free for reuse below
  }
  int e0 = w * chunk, e1 = min(E, e0 + chunk);
  for (int s0 = e0; s0 < e1; s0 += STAGE) {
    int s1 = min(e1, s0 + STAGE);
    int cnt = s1 - s0;
    for (int b = tid; b < B; b += 256) lexcl[b] = 0;
    __syncthreads();
    for (int e = s0 + tid; e < s1; e += 256) atomicAdd(&lexcl[dst[e] >> 6], 1);
    __syncthreads();
    // block exclusive scan of lexcl; init lcur
    int CH = (B + 255) >> 8;
    int b0 = tid * CH, b1 = min(B, b0 + CH);
    int s = 0;
    for (int b = b0; b < b1; b++) s += lexcl[b];
    part[tid] = s;
    __syncthreads();
    if (tid == 0) {
      int acc = 0;
      for (int i = 0; i < 256; i++) { int v = part[i]; part[i] = acc; acc += v; }
    }
    __syncthreads();
    int run = part[tid];
    for (int b = b0; b < b1; b++) {
      int v = lexcl[b];
      lexcl[b] = run;
      lcur[b] = run;
      run += v;
    }
    __syncthreads();
    // place records bucket-sorted into stage
    for (int e = s0 + tid; e < s1; e += 256) {
      int d = dst[e];
      int b = d >> 6;
      int p = atomicAdd(&lcur[b], 1);
      stage[p] = ((d & 63) << 17) | src[e];
      bdex[p] = (unsigned short)b;
    }
    __syncthreads();
    // p-linear write-out: consecutive p -> consecutive dest within runs
    for (int p = tid; p < cnt; p += 256) {
      int b = bdex[p];
      buck[gcur[b] + (p - lexcl[b])] = stage[p];
    }
    __syncthreads();
    // advance global bases by this sub-chunk's per-bucket counts
    for (int b = tid; b < B; b += 256) gcur[b] += lcur[b] - lexcl[b];
    __syncthreads();
  }
}

// ---------------- per-bucket counting sort -> exact per-node CSR ----------------
// 8-way replicated counters/cursors (bin[dl][rep], rep = tid&7): reduces
// same-address LDS atomic serialization. Slot order within a node's segment
// changes — permutation-invariant downstream.
__global__ __launch_bounds__(256) void k_bsort(const int* __restrict__ buck,
                                               const int* __restrict__ boff,
                                               int* __restrict__ csr,
                                               int* __restrict__ noff,
                                               float* __restrict__ dinv, int N) {
  __shared__ int bin[NB][8];
  __shared__ int excl[NB];
  int b = blockIdx.x, tid = threadIdx.x;
  const int rep = tid & 7;
  for (int i = tid; i < NB * 8; i += 256) ((int*)bin)[i] = 0;
  __syncthreads();
  int r0 = boff[b], r1 = boff[b + 1];
  for (int r = r0 + tid; r < r1; r += 256) atomicAdd(&bin[buck[r] >> 17][rep], 1);
  __syncthreads();
  if (tid < NB) {
    int t = 0;
#pragma unroll
    for (int r = 0; r < 8; r++) t += bin[tid][r];
    excl[tid] = t;
  }
  __syncthreads();
  if (tid == 0) {
    int acc = 0;
    for (int i = 0; i < NB; i++) { int v = excl[i]; excl[i] = acc; acc += v; }
  }
  __syncthreads();
  if (tid < NB) {
    int n = b * NB + tid;
    int tot = 0;
#pragma unroll
    for (int r = 0; r < 8; r++) tot += bin[tid][r];
    if (n < N) {
      dinv[n] = rsqrtf((float)tot + 1.0f);  // +1 self-loop
      noff[n] = r0 + excl[tid];
    }
    // replica cursors: disjoint sub-ranges of this node's segment
    int acc = excl[tid];
#pragma unroll
    for (int r = 0; r < 8; r++) { int c = bin[tid][r]; bin[tid][r] = acc; acc += c; }
  }
  if (b == gridDim.x - 1 && tid == 128) noff[N] = r1;  // r1 == E for last bucket
  __syncthreads();
  for (int r = r0 + tid; r < r1; r += 256) {
    int rec = buck[r];
    int p = atomicAdd(&bin[rec >> 17][rep], 1);
    csr[r0 + p] = rec & 0x1FFFF;
  }
}

// ============ MFMA GEMMs (mfma_f32_16x16x32_f16), all inputs fp16 ============
// A-frag:  A[m = lane&15][k = (lane>>4)*8 + j]
// D:       D[row = (lane>>4)*4 + reg][col = lane&15]

// ---------------- GEMM1: G = fp16((Xh @ W1) * dinv[row])   (Xh fp16 N x 128) ----------------
__global__ __launch_bounds__(256, 4) void k_gemm1(const unsigned short* __restrict__ Xh,
                                                  const unsigned short* __restrict__ fW1,
                                                  const float* __restrict__ dinv,
                                                  unsigned short* __restrict__ G, int N) {
  int tid = threadIdx.x;
  const int lane = tid & 63, wave = tid >> 6;
  const int m = lane & 15, q = lane >> 4;
  half8 bfrag[4][4];
#pragma unroll
  for (int c = 0; c < 4; c++)
#pragma unroll
    for (int t = 0; t < 4; t++)
      bfrag[c][t] = *reinterpret_cast<const half8*>(fW1 + ((c * 4 + t) * 64 + lane) * 8);
  int ntiles = (N + 15) >> 4;
  for (int tile = blockIdx.x * 4 + wave; tile < ntiles; tile += gridDim.x * 4) {
    int r0 = tile << 4;
    int rm = r0 + m; rm = rm < N ? rm : N - 1;
    floatx4 acc[4] = {{0.f,0.f,0.f,0.f},{0.f,0.f,0.f,0.f},{0.f,0.f,0.f,0.f},{0.f,0.f,0.f,0.f}};
#pragma unroll
    for (int c = 0; c < 4; c++) {
      half8 a = *reinterpret_cast<const half8*>(Xh + (size_t)rm * F_IN + c * 32 + q * 8);
#pragma unroll
      for (int t = 0; t < 4; t++)
        acc[t] = __builtin_amdgcn_mfma_f32_16x16x32_f16(a, bfrag[c][t], acc[t], 0, 0, 0);
    }
#pragma unroll
    for (int rr = 0; rr < 4; rr++) {
      int grow = r0 + q * 4 + rr;
      if (grow < N) {
        float dv = dinv[grow];
#pragma unroll
        for (int t = 0; t < 4; t++)
          G[(size_t)grow * F_HID + t * 16 + m] = f2h(acc[t][rr] * dv);
      }
    }
  }
}

// ---------------- GEMM2: G = fp16((O @ W2) * dinv[row])   (O fp16) ----------------
__global__ __launch_bounds__(256, 4) void k_gemm2(const unsigned short* __restrict__ O,
                                                  const unsigned short* __restrict__ fW2,
                                                  const float* __restrict__ dinv,
                                                  unsigned short* __restrict__ G, int N) {
  int tid = threadIdx.x;
  const int lane = tid & 63, wave = tid >> 6;
  const int m = lane & 15, q = lane >> 4;
  half8 bfrag[2][4];
#pragma unroll
  for (int c = 0; c < 2; c++)
#pragma unroll
    for (int t = 0; t < 4; t++)
      bfrag[c][t] = *reinterpret_cast<const half8*>(fW2 + ((c * 4 + t) * 64 + lane) * 8);
  int ntiles = (N + 15) >> 4;
  for (int tile = blockIdx.x * 4 + wave; tile < ntiles; tile += gridDim.x * 4) {
    int r0 = tile << 4;
    int rm = r0 + m; rm = rm < N ? rm : N - 1;
    floatx4 acc[4] = {{0.f,0.f,0.f,0.f},{0.f,0.f,0.f,0.f},{0.f,0.f,0.f,0.f},{0.f,0.f,0.f,0.f}};
#pragma unroll
    for (int c = 0; c < 2; c++) {
      half8 a = *reinterpret_cast<const half8*>(O + (size_t)rm * F_HID + c * 32 + q * 8);
#pragma unroll
      for (int t = 0; t < 4; t++)
        acc[t] = __builtin_amdgcn_mfma_f32_16x16x32_f16(a, bfrag[c][t], acc[t], 0, 0, 0);
    }
#pragma unroll
    for (int rr = 0; rr < 4; rr++) {
      int grow = r0 + q * 4 + rr;
      if (grow < N) {
        float dv = dinv[grow];
#pragma unroll
        for (int t = 0; t < 4; t++)
          G[(size_t)grow * F_HID + t * 16 + m] = f2h(acc[t][rr] * dv);
      }
    }
  }
}

// ---------------- aggregate: 4 rows/instruction group-gather + fused epilogue ----------------
template <bool RELU>
__global__ __launch_bounds__(256) void k_agg(const int* __restrict__ csr,
                                             const int* __restrict__ noff,
                                             const unsigned short* __restrict__ H,
                                             const float* __restrict__ dinv,
                                             const void* __restrict__ bias,
                                             unsigned short* __restrict__ OUT, int N,
                                             const int* __restrict__ flagp) {
  const bool isb = (*flagp != 0);
  const int lane = threadIdx.x & 63;
  const int g = lane >> 4, l16 = lane & 15;
  const int gw = (blockIdx.x * 256 + threadIdx.x) >> 6;
  const int nW = (gridDim.x * 256) >> 6;
  float bv[4];
#pragma unroll
  for (int d = 0; d < 4; d++)
    bv[d] = isb ? bf2f(((const unsigned short*)bias)[l16 * 4 + d])
                : ((const float*)bias)[l16 * 4 + d];
  for (int n = gw; n < N; n += nW) {
    int start = noff[n], end = noff[n + 1];
    float a0 = 0.f, a1 = 0.f, a2 = 0.f, a3 = 0.f;
    for (int e0 = start; e0 < end; e0 += 64) {
      int ee = e0 + lane;
      int idx = (ee < end) ? csr[ee] : 0;
      int m = end - e0; m = m < 64 ? m : 64;
      int nc = m >> 2;  // full 4-row chunks
      int c = 0;
      for (; c + 8 <= nc; c += 8) {  // 32 rows in flight
        int s[8];
#pragma unroll
        for (int u = 0; u < 8; u++) s[u] = __shfl(idx, (c + u) * 4 + g, 64);
        ushort4 v[8];
#pragma unroll
        for (int u = 0; u < 8; u++)
          v[u] = *reinterpret_cast<const ushort4*>(H + (size_t)s[u] * F_HID + l16 * 4);
#pragma unroll
        for (int u = 0; u < 8; u++) {
          a0 += h2f(v[u].x); a1 += h2f(v[u].y);
          a2 += h2f(v[u].z); a3 += h2f(v[u].w);
        }
      }
      for (; c < nc; c++) {
        int s0 = __shfl(idx, c * 4 + g, 64);
        ushort4 v0 = *reinterpret_cast<const ushort4*>(H + (size_t)s0 * F_HID + l16 * 4);
        a0 += h2f(v0.x); a1 += h2f(v0.y); a2 += h2f(v0.z); a3 += h2f(v0.w);
      }
      int rem = m & 3;
      if (rem) {
        int s0 = __shfl(idx, nc * 4 + g, 64);  // shfl outside divergence
        if (g < rem) {
          ushort4 v0 = *reinterpret_cast<const ushort4*>(H + (size_t)s0 * F_HID + l16 * 4);
          a0 += h2f(v0.x); a1 += h2f(v0.y); a2 += h2f(v0.z); a3 += h2f(v0.w);
        }
      }
    }
    // cross-group reduce (butterfly: all lanes end with totals)
    a0 += __shfl_xor(a0, 16, 64); a0 += __shfl_xor(a0, 32, 64);
    a1 += __shfl_xor(a1, 16, 64); a1 += __shfl_xor(a1, 32, 64);
    a2 += __shfl_xor(a2, 16, 64); a2 += __shfl_xor(a2, 32, 64);
    a3 += __shfl_xor(a3, 16, 64); a3 += __shfl_xor(a3, 32, 64);
    // self-loop + scale + bias (+relu), vector store by lanes 0-15
    ushort4 sv = *reinterpret_cast<const ushort4*>(H + (size_t)n * F_HID + l16 * 4);
    float dv = dinv[n];
    float o0 = (a0 + h2f(sv.x)) * dv + bv[0];
    float o1 = (a1 + h2f(sv.y)) * dv + bv[1];
    float o2 = (a2 + h2f(sv.z)) * dv + bv[2];
    float o3 = (a3 + h2f(sv.w)) * dv + bv[3];
    if (RELU) {
      o0 = fmaxf(o0, 0.f); o1 = fmaxf(o1, 0.f);
      o2 = fmaxf(o2, 0.f); o3 = fmaxf(o3, 0.f);
    }
    if (lane < 16) {
      ushort4 ov;
      ov.x = f2h(o0); ov.y = f2h(o1); ov.z = f2h(o2); ov.w = f2h(o3);
      *reinterpret_cast<ushort4*>(OUT + (size_t)n * F_HID + l16 * 4) = ov;
    }
  }
}

// ---------------- query: gather O[i], O[j]; on-the-fly MFMA MLP ----------------
// out[q] = relu(O[i]@Wa + O[j]@Wb + fc1_b) @ fc2_W + fc2_b
// 512-thread blocks (8 waves share the 32 KB weight copy), depth-1 pipelined
// gathers, sched_barrier acc-halving, setprio around MFMA. ~71 us — pinned at
// the L2/L3 random-line service rate (rounds 8-10 all plateau here).
__global__ __launch_bounds__(512) void k_query(const unsigned short* __restrict__ O,
                                               const unsigned short* __restrict__ fPR,
                                               const int* __restrict__ qi,
                                               const int* __restrict__ qj,
                                               const void* __restrict__ fc1b,
                                               const void* __restrict__ fc2W,
                                               const void* __restrict__ fc2b,
                                               void* __restrict__ out, int Q,
                                               const int* __restrict__ flagp) {
  __shared__ unsigned short sB[4 * 4096];  // 32 KB: fc1_W frag-order
  const bool isb = (*flagp != 0);
  int tid = threadIdx.x;
  {
    const uint4* srcp = reinterpret_cast<const uint4*>(fPR);
    uint4* dstp = reinterpret_cast<uint4*>(sB);
#pragma unroll
    for (int r = 0; r < 4; r++) dstp[tid + r * 512] = srcp[tid + r * 512];
  }
  const int lane = tid & 63, wave = tid >> 6;  // wave in [0,8)
  const int m_ = lane & 15, qk = lane >> 4;
  // per-lane epilogue LUT for hid cols h = T*16 + m_
  float bb[8], w0[8], w1[8];
#pragma unroll
  for (int T = 0; T < 8; T++) {
    int h = T * 16 + m_;
    if (isb) {
      bb[T] = bf2f(((const unsigned short*)fc1b)[h]);
      w0[T] = bf2f(((const unsigned short*)fc2W)[h * 2 + 0]);
      w1[T] = bf2f(((const unsigned short*)fc2W)[h * 2 + 1]);
    } else {
      bb[T] = ((const float*)fc1b)[h];
      w0[T] = ((const float*)fc2W)[h * 2 + 0];
      w1[T] = ((const float*)fc2W)[h * 2 + 1];
    }
  }
  float ob0 = isb ? bf2f(((const unsigned short*)fc2b)[0]) : ((const float*)fc2b)[0];
  float ob1 = isb ? bf2f(((const unsigned short*)fc2b)[1]) : ((const float*)fc2b)[1];
  __syncthreads();
  const half8* sBv = reinterpret_cast<const half8*>(sB);  // group stride 512 half8

  const int ntiles = (Q + 15) >> 4;
  const int nW = gridDim.x * 8;
  int tile = blockIdx.x * 8 + wave;
  if (tile >= ntiles) return;

  auto ldidx = [&](int t, int& iq, int& jq) {
    if (t < ntiles) {
      int q = t * 16 + m_;
      int qq = q < Q ? q : Q - 1;
      iq = qi[qq];
      jq = qj[qq];
    }  // else keep previous (harmless row re-gather)
  };
  auto gather = [&](int iq, int jq, half8& I0, half8& I1, half8& J0, half8& J1) {
    const half8* pI = reinterpret_cast<const half8*>(O + (size_t)iq * F_HID) + qk;
    const half8* pJ = reinterpret_cast<const half8*>(O + (size_t)jq * F_HID) + qk;
    I0 = pI[0]; I1 = pI[4];  // k 0-31 / 32-63
    J0 = pJ[0]; J1 = pJ[4];
  };

  // pipeline prologue: idx(t), rows(t), idx(t+1)
  int iqn = 0, jqn = 0;
  ldidx(tile, iqn, jqn);
  half8 I0, I1, J0, J1;
  gather(iqn, jqn, I0, I1, J0, J1);
  ldidx(tile + nW, iqn, jqn);

  for (; tile < ntiles; tile += nW) {
    // issue NEXT tile's row gathers + the tile after's index loads first;
    // they drain while we compute the current tile.
    half8 nI0, nI1, nJ0, nJ1;
    gather(iqn, jqn, nI0, nI1, nJ0, nJ1);
    ldidx(tile + 2 * nW, iqn, jqn);

    float r0[4] = {0.f, 0.f, 0.f, 0.f};
    float r1[4] = {0.f, 0.f, 0.f, 0.f};
    const floatx4 zz = {0.f, 0.f, 0.f, 0.f};
#pragma unroll
    for (int h = 0; h < 2; h++) {  // hid col half: groups {h (Wa), 2+h (Wb)}
      floatx4 acc[4];
#pragma unroll
      for (int tt = 0; tt < 4; tt++) acc[tt] = zz;
      __builtin_amdgcn_s_setprio(1);
#pragma unroll
      for (int tt = 0; tt < 4; tt++) {
        acc[tt] = __builtin_amdgcn_mfma_f32_16x16x32_f16(
            I0, sBv[h * 512 + tt * 64 + lane], acc[tt], 0, 0, 0);
        acc[tt] = __builtin_amdgcn_mfma_f32_16x16x32_f16(
            I1, sBv[h * 512 + (4 + tt) * 64 + lane], acc[tt], 0, 0, 0);
        acc[tt] = __builtin_amdgcn_mfma_f32_16x16x32_f16(
            J0, sBv[(2 + h) * 512 + tt * 64 + lane], acc[tt], 0, 0, 0);
        acc[tt] = __builtin_amdgcn_mfma_f32_16x16x32_f16(
            J1, sBv[(2 + h) * 512 + (4 + tt) * 64 + lane], acc[tt], 0, 0, 0);
      }
      __builtin_amdgcn_s_setprio(0);
      // partial epilogue for this half: fold into persistent r0/r1
#pragma unroll
      for (int tt = 0; tt < 4; tt++) {
        int T = h * 4 + tt;  // hid col = T*16 + m_
#pragma unroll
        for (int rr = 0; rr < 4; rr++) {
          float hv = fmaxf(acc[tt][rr] + bb[T], 0.f);
          r0[rr] += hv * w0[T];
          r1[rr] += hv * w1[T];
        }
      }
      // pin half-1's MFMAs after half-0's fold: halves acc liveness (16 AGPR)
      __builtin_amdgcn_sched_barrier(0);
    }
    // reduce across the 16 lanes of each q-group and store
#pragma unroll
    for (int rr = 0; rr < 4; rr++) {
      float a0 = r0[rr], a1 = r1[rr];
#pragma unroll
      for (int off = 8; off > 0; off >>= 1) {
        a0 += __shfl_xor(a0, off, 16);
        a1 += __shfl_xor(a1, off, 16);
      }
      if (m_ == 0) {
        int q = tile * 16 + qk * 4 + rr;
        if (q < Q) {
          if (isb) {
            *reinterpret_cast<ushort2*>((unsigned short*)out + (size_t)q * 2) =
                make_ushort2(f2bf(a0 + ob0), f2bf(a1 + ob1));
          } else {
            *reinterpret_cast<float2*>((float*)out + (size_t)q * 2) =
                make_float2(a0 + ob0, a1 + ob1);
          }
        }
      }
    }
    // rotate pipeline buffers
    I0 = nI0; I1 = nI1; J0 = nJ0; J1 = nJ1;
  }
}

extern "C" void kernel_launch(void* const* d_in, const int* in_sizes, int n_in,
                              void* d_out, int out_size, void* d_ws, size_t ws_size,
                              hipStream_t stream) {
  const void* X    = d_in[0];
  const int*  edges= (const int*)d_in[1];
  const int*  qi   = (const int*)d_in[2];
  const int*  qj   = (const int*)d_in[3];
  const void* W1   = d_in[4];
  const void* b1   = d_in[5];
  const void* W2   = d_in[6];
  const void* b2   = d_in[7];
  const void* fc1W = d_in[8];
  const void* fc1b = d_in[9];
  const void* fc2W = d_in[10];
  const void* fc2b = d_in[11];

  const int N = in_sizes[0] / F_IN;
  const int E = in_sizes[1] / 2;
  const int Q = in_sizes[2];
  const int B = (N + NB - 1) / NB;           // buckets (<= MAXB for N <= 131072)
  const int chunk = (E + NWG - 1) / NWG;

  char* ws = (char*)d_ws;
  size_t off = 0;
  auto alloc = [&](size_t bytes) -> void* {
    void* p = ws + off;
    off += (bytes + 255) & ~(size_t)255;
    return p;
  };
  int*            flag = (int*)alloc(4);
  float*          dinv = (float*)alloc((size_t)N * 4);
  unsigned short* Xh   = (unsigned short*)alloc((size_t)N * F_IN * 2);   // fp16 X
  unsigned short* G    = (unsigned short*)alloc((size_t)N * F_HID * 2);  // gemm out (fp16)
  unsigned short* O    = (unsigned short*)alloc((size_t)N * F_HID * 2);  // layer out (fp16)
  unsigned short* fW1  = (unsigned short*)alloc((size_t)F_IN * F_HID * 2);   // frag-order fp16
  unsigned short* fW2  = (unsigned short*)alloc((size_t)F_HID * F_HID * 2);
  unsigned short* fPR  = (unsigned short*)alloc((size_t)4 * F_HID * 64 * 2);
  // bucket/CSR scratch
  int* hist = (int*)alloc((size_t)NWG * B * 4);
  int* btot = (int*)alloc((size_t)(B + 1) * 4);
  int* boff = (int*)alloc((size_t)(B + 1) * 4);
  int* buck = (int*)alloc((size_t)E * 4);
  int* csr  = (int*)alloc((size_t)E * 4);
  int* noff = (int*)alloc((size_t)(N + 1) * 4);
  (void)ws_size; (void)n_in; (void)out_size;

  const int* esrc = edges;
  const int* edst = edges + E;

  k_detect<<<1, 64, 0, stream>>>((const unsigned int*)X, flag);
  // fused xcast + weight prep + edge histogram (mutually independent)
  k_front<<<2048, 256, 0, stream>>>(X, Xh, N * F_IN / 8, W1, W2, fc1W, fW1, fW2, fPR,
                                    edst, hist, E, B, chunk, flag);

  // bucket scan + fill (bscan2 fused) + per-bucket counting sort -> CSR/dinv
  k_bscan1<<<(B + 3) / 4, 256, 0, stream>>>(hist, btot, B);
  k_bfill<<<NWG, 256, 0, stream>>>(esrc, edst, hist, btot, boff, buck, E, B, chunk);
  k_bsort<<<B, 256, 0, stream>>>(buck, boff, csr, noff, dinv, N);

  // layer 1
  k_gemm1<<<2048, 256, 0, stream>>>(Xh, fW1, dinv, G, N);
  k_agg<true><<<2048, 256, 0, stream>>>(csr, noff, G, dinv, b1, O, N, flag);

  // layer 2
  k_gemm2<<<2048, 256, 0, stream>>>(O, fW2, dinv, G, N);
  k_agg<false><<<2048, 256, 0, stream>>>(csr, noff, G, dinv, b2, O, N, flag);

  // per-query: gather O[i], O[j]; MFMA MLP on the fly (512-thread blocks)
  k_query<<<1024, 512, 0, stream>>>(O, fPR, qi, qj, fc1b, fc2W, fc2b, d_out, Q, flag);
}

// Round 14
// 412.201 us; speedup vs baseline: 1.1299x; 1.0585x over previous
//
#include <hip/hip_runtime.h>
#include <hip/hip_bf16.h>
#include <hip/hip_fp16.h>
#include <cstdint>

#define F_IN 128
#define F_HID 64
#define NB 64          // nodes per bucket
#define MAXB 2048      // max buckets (N <= 131072)
#define NWG 512        // WGs for hist/fill edge partition (2 blocks/CU in bfill)
#define PREPB 16       // prep blocks inside k_front
#define STAGE 6400     // k_bfill LDS staging capacity (63.4 KB total -> 2 blocks/CU)

typedef _Float16 half8 __attribute__((ext_vector_type(8)));
typedef float floatx4 __attribute__((ext_vector_type(4)));

__device__ __forceinline__ float bf2f(unsigned short u) {
  return __uint_as_float(((unsigned int)u) << 16);
}
__device__ __forceinline__ unsigned short f2bf(float f) {
  unsigned int u = __float_as_uint(f);
  u += 0x7FFFu + ((u >> 16) & 1u);   // round-to-nearest-even
  return (unsigned short)(u >> 16);
}
__device__ __forceinline__ float h2f(unsigned short u) {
  return __half2float(__ushort_as_half(u));
}
__device__ __forceinline__ unsigned short f2h(float f) {
  return __half_as_ushort(__float2half(f));
}

// ---------------- dtype detection kernel (round-12 lesson: do NOT inline —
// per-block redundant 256-word scans cost k_query +10us and k_agg +10us) ----
__global__ __launch_bounds__(64) void k_detect(const unsigned int* __restrict__ Xw,
                                               int* __restrict__ flag) {
  int lane = threadIdx.x;
  int cnt = 0;
  for (int t = lane; t < 256; t += 64) {
    unsigned int ex = (Xw[t] >> 7) & 0xFFu;
    cnt += (ex >= 117u && ex <= 137u) ? 1 : 0;
  }
#pragma unroll
  for (int off = 32; off > 0; off >>= 1) cnt += __shfl_xor(cnt, off, 64);
  if (lane == 0) *flag = (cnt >= 128) ? 1 : 0;  // 1 = bf16, 0 = fp32
}

// ---------------- fused front: bhist | weight-prep | xcast (independent) ----------------
// blocks [0,NWG): edge histogram; [NWG,NWG+PREPB): weight prep; rest: X cast.
__global__ __launch_bounds__(256) void k_front(const void* __restrict__ Xv,
                                               unsigned short* __restrict__ Xh, int total8,
                                               const void* __restrict__ W1v,
                                               const void* __restrict__ W2v,
                                               const void* __restrict__ fc1Wv,
                                               unsigned short* __restrict__ fW1,
                                               unsigned short* __restrict__ fW2,
                                               unsigned short* __restrict__ fPR,
                                               const int* __restrict__ dst,
                                               int* __restrict__ hist, int E, int B, int chunk,
                                               const int* __restrict__ flagp) {
  __shared__ int lh[MAXB];
  const int bid = blockIdx.x;
  if (bid < NWG) {  // ---- bhist ----
    int w = bid, tid = threadIdx.x;
    for (int b = tid; b < B; b += 256) lh[b] = 0;
    __syncthreads();
    int e0 = w * chunk, e1 = min(E, e0 + chunk);
    for (int e = e0 + tid; e < e1; e += 256) atomicAdd(&lh[dst[e] >> 6], 1);
    __syncthreads();
    for (int b = tid; b < B; b += 256) hist[w * B + b] = lh[b];
    return;
  }
  const bool isb = (*flagp != 0);
  if (bid < NWG + PREPB) {  // ---- weight prep (frag-order fp16) ----
    // B-frag for mfma_f32_16x16x32_f16: B[k=(lane>>4)*8+j][n=lane&15].
    // dest (ushorts) for W element (k,n): c=k>>5,q=(k>>3)&3,j=k&7,t=n>>4,m=n&15
    //   -> ((c*4+t)*64 + q*16+m)*8 + j
    int tid = (bid - NWG) * 256 + threadIdx.x;
    int stride = PREPB * 256;
    for (int e = tid; e < F_IN * F_HID; e += stride) {
      int k = e >> 6, n = e & 63;
      unsigned short v = isb ? f2h(bf2f(((const unsigned short*)W1v)[e]))
                             : f2h(((const float*)W1v)[e]);
      int c = k >> 5, q = (k >> 3) & 3, j = k & 7, t = n >> 4, m = n & 15;
      fW1[((c * 4 + t) * 64 + q * 16 + m) * 8 + j] = v;
    }
    for (int e = tid; e < F_HID * F_HID; e += stride) {
      int k = e >> 6, n = e & 63;
      unsigned short v = isb ? f2h(bf2f(((const unsigned short*)W2v)[e]))
                             : f2h(((const float*)W2v)[e]);
      int c = k >> 5, q = (k >> 3) & 3, j = k & 7, t = n >> 4, m = n & 15;
      fW2[((c * 4 + t) * 64 + q * 16 + m) * 8 + j] = v;
    }
    // fc1_W, 4 groups of 64x64: g&2 row half (Wa/Wb), g&1 col half
    for (int ge = tid; ge < 4 * F_HID * 64; ge += stride) {
      int g = ge >> 12, e = ge & 4095;
      int k = e >> 6, n = e & 63;
      int src = (((g & 2) ? 64 : 0) + k) * 128 + (g & 1) * 64 + n;
      unsigned short v = isb ? f2h(bf2f(((const unsigned short*)fc1Wv)[src]))
                             : f2h(((const float*)fc1Wv)[src]);
      int c = k >> 5, q = (k >> 3) & 3, j = k & 7, t = n >> 4, m = n & 15;
      fPR[g * 4096 + ((c * 4 + t) * 64 + q * 16 + m) * 8 + j] = v;
    }
    return;
  }
  // ---- xcast: lane-linear streaming bf16/fp32 -> fp16 ----
  int t = (bid - (NWG + PREPB)) * 256 + threadIdx.x;
  int stride = (gridDim.x - (NWG + PREPB)) * 256;
  for (; t < total8; t += stride) {
    unsigned short r[8];
    if (isb) {
      uint4 d = reinterpret_cast<const uint4*>(Xv)[t];  // 8 bf16
      r[0] = f2h(__uint_as_float(d.x << 16));
      r[1] = f2h(__uint_as_float(d.x & 0xFFFF0000u));
      r[2] = f2h(__uint_as_float(d.y << 16));
      r[3] = f2h(__uint_as_float(d.y & 0xFFFF0000u));
      r[4] = f2h(__uint_as_float(d.z << 16));
      r[5] = f2h(__uint_as_float(d.z & 0xFFFF0000u));
      r[6] = f2h(__uint_as_float(d.w << 16));
      r[7] = f2h(__uint_as_float(d.w & 0xFFFF0000u));
    } else {
      float4 a = reinterpret_cast<const float4*>(Xv)[2 * t];
      float4 b = reinterpret_cast<const float4*>(Xv)[2 * t + 1];
      r[0] = f2h(a.x); r[1] = f2h(a.y); r[2] = f2h(a.z); r[3] = f2h(a.w);
      r[4] = f2h(b.x); r[5] = f2h(b.y); r[6] = f2h(b.z); r[7] = f2h(b.w);
    }
    uint4 o;
    o.x = (unsigned int)r[0] | ((unsigned int)r[1] << 16);
    o.y = (unsigned int)r[2] | ((unsigned int)r[3] << 16);
    o.z = (unsigned int)r[4] | ((unsigned int)r[5] << 16);
    o.w = (unsigned int)r[6] | ((unsigned int)r[7] << 16);
    reinterpret_cast<uint4*>(Xh)[t] = o;
  }
}

// ---------------- bscan1: wave-per-bucket parallel scan over W=NWG ----------------
__global__ __launch_bounds__(256) void k_bscan1(int* __restrict__ hist,
                                                int* __restrict__ btot, int B) {
  const int WPL = NWG / 64;  // hist entries per lane
  int b = (blockIdx.x * 256 + threadIdx.x) >> 6;  // bucket = global wave id
  int lane = threadIdx.x & 63;
  if (b >= B) return;
  int v[WPL];
  int s = 0;
#pragma unroll
  for (int k = 0; k < WPL; k++) {
    v[k] = hist[(size_t)(lane * WPL + k) * B + b];
    s += v[k];
  }
  // inclusive scan of s across 64 lanes -> exclusive prefix
  int pre = s;
#pragma unroll
  for (int off = 1; off < 64; off <<= 1) {
    int t = __shfl_up(pre, off, 64);
    if (lane >= off) pre += t;
  }
  int running = pre - s;  // exclusive
#pragma unroll
  for (int k = 0; k < WPL; k++) {
    int val = v[k];
    hist[(size_t)(lane * WPL + k) * B + b] = running;
    running += val;
  }
  if (lane == 63) btot[b] = running;  // bucket total
}

// ---------------- bfill: LDS-staged counting sort + fused bucket-base scan ----------------
// bscan2 fused: each block computes boff locally from btot; block 0 publishes
// global boff for k_bsort. LDS-staged binning: write p-linearly so consecutive
// lanes write consecutive buck[] slots. STAGE=6400 keeps LDS at ~63 KB so
// 2 blocks/CU fit (round-13: 102 KB -> 1 block/CU -> 8.6% occupancy was the
// wall). With NWG=512, chunk ~= 6250 <= STAGE: single staging pass per block.
// record = (dst_local << 17) | src (needs N <= 131072).
__global__ __launch_bounds__(256) void k_bfill(const int* __restrict__ src,
                                               const int* __restrict__ dst,
                                               const int* __restrict__ hist,
                                               const int* __restrict__ btot,
                                               int* __restrict__ boff,
                                               int* __restrict__ buck,
                                               int E, int B, int chunk) {
  __shared__ int gcur[MAXB];                 // global write base per bucket
  __shared__ int lexcl[MAXB];                // local excl offsets (temp: boff)
  __shared__ int lcur[MAXB];                 // placement cursors
  __shared__ int stage[STAGE];               // bucket-sorted records
  __shared__ unsigned short bdex[STAGE];     // bucket id per staged slot
  __shared__ int part[256];
  const int w = blockIdx.x, tid = threadIdx.x;
  // ---- fused bscan2: local exclusive scan of btot -> bucket bases ----
  {
    int CH = (B + 255) >> 8;
    int b0 = tid * CH, b1 = min(B, b0 + CH);
    int s = 0;
    for (int b = b0; b < b1; b++) s += btot[b];
    part[tid] = s;
    __syncthreads();
    if (tid == 0) {
      int acc = 0;
      for (int i = 0; i < 256; i++) { int v = part[i]; part[i] = acc; acc += v; }
    }
    __syncthreads();
    int run = part[tid];
    for (int b = b0; b < b1; b++) { lexcl[b] = run; run += btot[b]; }
    __syncthreads();
    for (int b = tid; b < B; b += 256) gcur[b] = lexcl[b] + hist[w * B + b];
    if (w == 0) {  // publish for k_bsort
      for (int b = tid; b < B; b += 256) boff[b] = lexcl[b];
      if (tid == 0) boff[B] = E;
    }
    __syncthreads();  // lexcl free for reuse below
  }
  int e0 = w * chunk, e1 = min(E, e0 + chunk);
  for (int s0 = e0; s0 < e1; s0 += STAGE) {
    int s1 = min(e1, s0 + STAGE);
    int cnt = s1 - s0;
    for (int b = tid; b < B; b += 256) lexcl[b] = 0;
    __syncthreads();
    for (int e = s0 + tid; e < s1; e += 256) atomicAdd(&lexcl[dst[e] >> 6], 1);
    __syncthreads();
    // block exclusive scan of lexcl; init lcur
    int CH = (B + 255) >> 8;
    int b0 = tid * CH, b1 = min(B, b0 + CH);
    int s = 0;
    for (int b = b0; b < b1; b++) s += lexcl[b];
    part[tid] = s;
    __syncthreads();
    if (tid == 0) {
      int acc = 0;
      for (int i = 0; i < 256; i++) { int v = part[i]; part[i] = acc; acc += v; }
    }
    __syncthreads();
    int run = part[tid];
    for (int b = b0; b < b1; b++) {
      int v = lexcl[b];
      lexcl[b] = run;
      lcur[b] = run;
      run += v;
    }
    __syncthreads();
    // place records bucket-sorted into stage
    for (int e = s0 + tid; e < s1; e += 256) {
      int d = dst[e];
      int b = d >> 6;
      int p = atomicAdd(&lcur[b], 1);
      stage[p] = ((d & 63) << 17) | src[e];
      bdex[p] = (unsigned short)b;
    }
    __syncthreads();
    // p-linear write-out: consecutive p -> consecutive dest within runs
    for (int p = tid; p < cnt; p += 256) {
      int b = bdex[p];
      buck[gcur[b] + (p - lexcl[b])] = stage[p];
    }
    __syncthreads();
    // advance global bases by this sub-chunk's per-bucket counts
    for (int b = tid; b < B; b += 256) gcur[b] += lcur[b] - lexcl[b];
    __syncthreads();
  }
}

// ---------------- per-bucket counting sort -> exact per-node CSR ----------------
// 8-way replicated counters/cursors (bin[dl][rep], rep = tid&7): reduces
// same-address LDS atomic serialization. Slot order within a node's segment
// changes — permutation-invariant downstream.
__global__ __launch_bounds__(256) void k_bsort(const int* __restrict__ buck,
                                               const int* __restrict__ boff,
                                               int* __restrict__ csr,
                                               int* __restrict__ noff,
                                               float* __restrict__ dinv, int N) {
  __shared__ int bin[NB][8];
  __shared__ int excl[NB];
  int b = blockIdx.x, tid = threadIdx.x;
  const int rep = tid & 7;
  for (int i = tid; i < NB * 8; i += 256) ((int*)bin)[i] = 0;
  __syncthreads();
  int r0 = boff[b], r1 = boff[b + 1];
  for (int r = r0 + tid; r < r1; r += 256) atomicAdd(&bin[buck[r] >> 17][rep], 1);
  __syncthreads();
  if (tid < NB) {
    int t = 0;
#pragma unroll
    for (int r = 0; r < 8; r++) t += bin[tid][r];
    excl[tid] = t;
  }
  __syncthreads();
  if (tid == 0) {
    int acc = 0;
    for (int i = 0; i < NB; i++) { int v = excl[i]; excl[i] = acc; acc += v; }
  }
  __syncthreads();
  if (tid < NB) {
    int n = b * NB + tid;
    int tot = 0;
#pragma unroll
    for (int r = 0; r < 8; r++) tot += bin[tid][r];
    if (n < N) {
      dinv[n] = rsqrtf((float)tot + 1.0f);  // +1 self-loop
      noff[n] = r0 + excl[tid];
    }
    // replica cursors: disjoint sub-ranges of this node's segment
    int acc = excl[tid];
#pragma unroll
    for (int r = 0; r < 8; r++) { int c = bin[tid][r]; bin[tid][r] = acc; acc += c; }
  }
  if (b == gridDim.x - 1 && tid == 128) noff[N] = r1;  // r1 == E for last bucket
  __syncthreads();
  for (int r = r0 + tid; r < r1; r += 256) {
    int rec = buck[r];
    int p = atomicAdd(&bin[rec >> 17][rep], 1);
    csr[r0 + p] = rec & 0x1FFFF;
  }
}

// ============ MFMA GEMMs (mfma_f32_16x16x32_f16), all inputs fp16 ============
// A-frag:  A[m = lane&15][k = (lane>>4)*8 + j]
// D:       D[row = (lane>>4)*4 + reg][col = lane&15]

// ---------------- GEMM1: G = fp16((Xh @ W1) * dinv[row])   (Xh fp16 N x 128) ----------------
__global__ __launch_bounds__(256, 4) void k_gemm1(const unsigned short* __restrict__ Xh,
                                                  const unsigned short* __restrict__ fW1,
                                                  const float* __restrict__ dinv,
                                                  unsigned short* __restrict__ G, int N) {
  int tid = threadIdx.x;
  const int lane = tid & 63, wave = tid >> 6;
  const int m = lane & 15, q = lane >> 4;
  half8 bfrag[4][4];
#pragma unroll
  for (int c = 0; c < 4; c++)
#pragma unroll
    for (int t = 0; t < 4; t++)
      bfrag[c][t] = *reinterpret_cast<const half8*>(fW1 + ((c * 4 + t) * 64 + lane) * 8);
  int ntiles = (N + 15) >> 4;
  for (int tile = blockIdx.x * 4 + wave; tile < ntiles; tile += gridDim.x * 4) {
    int r0 = tile << 4;
    int rm = r0 + m; rm = rm < N ? rm : N - 1;
    floatx4 acc[4] = {{0.f,0.f,0.f,0.f},{0.f,0.f,0.f,0.f},{0.f,0.f,0.f,0.f},{0.f,0.f,0.f,0.f}};
#pragma unroll
    for (int c = 0; c < 4; c++) {
      half8 a = *reinterpret_cast<const half8*>(Xh + (size_t)rm * F_IN + c * 32 + q * 8);
#pragma unroll
      for (int t = 0; t < 4; t++)
        acc[t] = __builtin_amdgcn_mfma_f32_16x16x32_f16(a, bfrag[c][t], acc[t], 0, 0, 0);
    }
#pragma unroll
    for (int rr = 0; rr < 4; rr++) {
      int grow = r0 + q * 4 + rr;
      if (grow < N) {
        float dv = dinv[grow];
#pragma unroll
        for (int t = 0; t < 4; t++)
          G[(size_t)grow * F_HID + t * 16 + m] = f2h(acc[t][rr] * dv);
      }
    }
  }
}

// ---------------- GEMM2: G = fp16((O @ W2) * dinv[row])   (O fp16) ----------------
__global__ __launch_bounds__(256, 4) void k_gemm2(const unsigned short* __restrict__ O,
                                                  const unsigned short* __restrict__ fW2,
                                                  const float* __restrict__ dinv,
                                                  unsigned short* __restrict__ G, int N) {
  int tid = threadIdx.x;
  const int lane = tid & 63, wave = tid >> 6;
  const int m = lane & 15, q = lane >> 4;
  half8 bfrag[2][4];
#pragma unroll
  for (int c = 0; c < 2; c++)
#pragma unroll
    for (int t = 0; t < 4; t++)
      bfrag[c][t] = *reinterpret_cast<const half8*>(fW2 + ((c * 4 + t) * 64 + lane) * 8);
  int ntiles = (N + 15) >> 4;
  for (int tile = blockIdx.x * 4 + wave; tile < ntiles; tile += gridDim.x * 4) {
    int r0 = tile << 4;
    int rm = r0 + m; rm = rm < N ? rm : N - 1;
    floatx4 acc[4] = {{0.f,0.f,0.f,0.f},{0.f,0.f,0.f,0.f},{0.f,0.f,0.f,0.f},{0.f,0.f,0.f,0.f}};
#pragma unroll
    for (int c = 0; c < 2; c++) {
      half8 a = *reinterpret_cast<const half8*>(O + (size_t)rm * F_HID + c * 32 + q * 8);
#pragma unroll
      for (int t = 0; t < 4; t++)
        acc[t] = __builtin_amdgcn_mfma_f32_16x16x32_f16(a, bfrag[c][t], acc[t], 0, 0, 0);
    }
#pragma unroll
    for (int rr = 0; rr < 4; rr++) {
      int grow = r0 + q * 4 + rr;
      if (grow < N) {
        float dv = dinv[grow];
#pragma unroll
        for (int t = 0; t < 4; t++)
          G[(size_t)grow * F_HID + t * 16 + m] = f2h(acc[t][rr] * dv);
      }
    }
  }
}

// ---------------- aggregate: 4 rows/instruction group-gather + fused epilogue ----------------
template <bool RELU>
__global__ __launch_bounds__(256) void k_agg(const int* __restrict__ csr,
                                             const int* __restrict__ noff,
                                             const unsigned short* __restrict__ H,
                                             const float* __restrict__ dinv,
                                             const void* __restrict__ bias,
                                             unsigned short* __restrict__ OUT, int N,
                                             const int* __restrict__ flagp) {
  const bool isb = (*flagp != 0);
  const int lane = threadIdx.x & 63;
  const int g = lane >> 4, l16 = lane & 15;
  const int gw = (blockIdx.x * 256 + threadIdx.x) >> 6;
  const int nW = (gridDim.x * 256) >> 6;
  float bv[4];
#pragma unroll
  for (int d = 0; d < 4; d++)
    bv[d] = isb ? bf2f(((const unsigned short*)bias)[l16 * 4 + d])
                : ((const float*)bias)[l16 * 4 + d];
  for (int n = gw; n < N; n += nW) {
    int start = noff[n], end = noff[n + 1];
    float a0 = 0.f, a1 = 0.f, a2 = 0.f, a3 = 0.f;
    for (int e0 = start; e0 < end; e0 += 64) {
      int ee = e0 + lane;
      int idx = (ee < end) ? csr[ee] : 0;
      int m = end - e0; m = m < 64 ? m : 64;
      int nc = m >> 2;  // full 4-row chunks
      int c = 0;
      for (; c + 8 <= nc; c += 8) {  // 32 rows in flight
        int s[8];
#pragma unroll
        for (int u = 0; u < 8; u++) s[u] = __shfl(idx, (c + u) * 4 + g, 64);
        ushort4 v[8];
#pragma unroll
        for (int u = 0; u < 8; u++)
          v[u] = *reinterpret_cast<const ushort4*>(H + (size_t)s[u] * F_HID + l16 * 4);
#pragma unroll
        for (int u = 0; u < 8; u++) {
          a0 += h2f(v[u].x); a1 += h2f(v[u].y);
          a2 += h2f(v[u].z); a3 += h2f(v[u].w);
        }
      }
      for (; c < nc; c++) {
        int s0 = __shfl(idx, c * 4 + g, 64);
        ushort4 v0 = *reinterpret_cast<const ushort4*>(H + (size_t)s0 * F_HID + l16 * 4);
        a0 += h2f(v0.x); a1 += h2f(v0.y); a2 += h2f(v0.z); a3 += h2f(v0.w);
      }
      int rem = m & 3;
      if (rem) {
        int s0 = __shfl(idx, nc * 4 + g, 64);  // shfl outside divergence
        if (g < rem) {
          ushort4 v0 = *reinterpret_cast<const ushort4*>(H + (size_t)s0 * F_HID + l16 * 4);
          a0 += h2f(v0.x); a1 += h2f(v0.y); a2 += h2f(v0.z); a3 += h2f(v0.w);
        }
      }
    }
    // cross-group reduce (butterfly: all lanes end with totals)
    a0 += __shfl_xor(a0, 16, 64); a0 += __shfl_xor(a0, 32, 64);
    a1 += __shfl_xor(a1, 16, 64); a1 += __shfl_xor(a1, 32, 64);
    a2 += __shfl_xor(a2, 16, 64); a2 += __shfl_xor(a2, 32, 64);
    a3 += __shfl_xor(a3, 16, 64); a3 += __shfl_xor(a3, 32, 64);
    // self-loop + scale + bias (+relu), vector store by lanes 0-15
    ushort4 sv = *reinterpret_cast<const ushort4*>(H + (size_t)n * F_HID + l16 * 4);
    float dv = dinv[n];
    float o0 = (a0 + h2f(sv.x)) * dv + bv[0];
    float o1 = (a1 + h2f(sv.y)) * dv + bv[1];
    float o2 = (a2 + h2f(sv.z)) * dv + bv[2];
    float o3 = (a3 + h2f(sv.w)) * dv + bv[3];
    if (RELU) {
      o0 = fmaxf(o0, 0.f); o1 = fmaxf(o1, 0.f);
      o2 = fmaxf(o2, 0.f); o3 = fmaxf(o3, 0.f);
    }
    if (lane < 16) {
      ushort4 ov;
      ov.x = f2h(o0); ov.y = f2h(o1); ov.z = f2h(o2); ov.w = f2h(o3);
      *reinterpret_cast<ushort4*>(OUT + (size_t)n * F_HID + l16 * 4) = ov;
    }
  }
}

// ---------------- query: gather O[i], O[j]; on-the-fly MFMA MLP ----------------
// out[q] = relu(O[i]@Wa + O[j]@Wb + fc1_b) @ fc2_W + fc2_b
// 512-thread blocks (8 waves share the 32 KB weight copy), depth-1 pipelined
// gathers, sched_barrier acc-halving, setprio around MFMA. ~71 us — pinned at
// the L2/L3 random-line service rate (rounds 8-10 all plateau here).
__global__ __launch_bounds__(512) void k_query(const unsigned short* __restrict__ O,
                                               const unsigned short* __restrict__ fPR,
                                               const int* __restrict__ qi,
                                               const int* __restrict__ qj,
                                               const void* __restrict__ fc1b,
                                               const void* __restrict__ fc2W,
                                               const void* __restrict__ fc2b,
                                               void* __restrict__ out, int Q,
                                               const int* __restrict__ flagp) {
  __shared__ unsigned short sB[4 * 4096];  // 32 KB: fc1_W frag-order
  const bool isb = (*flagp != 0);
  int tid = threadIdx.x;
  {
    const uint4* srcp = reinterpret_cast<const uint4*>(fPR);
    uint4* dstp = reinterpret_cast<uint4*>(sB);
#pragma unroll
    for (int r = 0; r < 4; r++) dstp[tid + r * 512] = srcp[tid + r * 512];
  }
  const int lane = tid & 63, wave = tid >> 6;  // wave in [0,8)
  const int m_ = lane & 15, qk = lane >> 4;
  // per-lane epilogue LUT for hid cols h = T*16 + m_
  float bb[8], w0[8], w1[8];
#pragma unroll
  for (int T = 0; T < 8; T++) {
    int h = T * 16 + m_;
    if (isb) {
      bb[T] = bf2f(((const unsigned short*)fc1b)[h]);
      w0[T] = bf2f(((const unsigned short*)fc2W)[h * 2 + 0]);
      w1[T] = bf2f(((const unsigned short*)fc2W)[h * 2 + 1]);
    } else {
      bb[T] = ((const float*)fc1b)[h];
      w0[T] = ((const float*)fc2W)[h * 2 + 0];
      w1[T] = ((const float*)fc2W)[h * 2 + 1];
    }
  }
  float ob0 = isb ? bf2f(((const unsigned short*)fc2b)[0]) : ((const float*)fc2b)[0];
  float ob1 = isb ? bf2f(((const unsigned short*)fc2b)[1]) : ((const float*)fc2b)[1];
  __syncthreads();
  const half8* sBv = reinterpret_cast<const half8*>(sB);  // group stride 512 half8

  const int ntiles = (Q + 15) >> 4;
  const int nW = gridDim.x * 8;
  int tile = blockIdx.x * 8 + wave;
  if (tile >= ntiles) return;

  auto ldidx = [&](int t, int& iq, int& jq) {
    if (t < ntiles) {
      int q = t * 16 + m_;
      int qq = q < Q ? q : Q - 1;
      iq = qi[qq];
      jq = qj[qq];
    }  // else keep previous (harmless row re-gather)
  };
  auto gather = [&](int iq, int jq, half8& I0, half8& I1, half8& J0, half8& J1) {
    const half8* pI = reinterpret_cast<const half8*>(O + (size_t)iq * F_HID) + qk;
    const half8* pJ = reinterpret_cast<const half8*>(O + (size_t)jq * F_HID) + qk;
    I0 = pI[0]; I1 = pI[4];  // k 0-31 / 32-63
    J0 = pJ[0]; J1 = pJ[4];
  };

  // pipeline prologue: idx(t), rows(t), idx(t+1)
  int iqn = 0, jqn = 0;
  ldidx(tile, iqn, jqn);
  half8 I0, I1, J0, J1;
  gather(iqn, jqn, I0, I1, J0, J1);
  ldidx(tile + nW, iqn, jqn);

  for (; tile < ntiles; tile += nW) {
    // issue NEXT tile's row gathers + the tile after's index loads first;
    // they drain while we compute the current tile.
    half8 nI0, nI1, nJ0, nJ1;
    gather(iqn, jqn, nI0, nI1, nJ0, nJ1);
    ldidx(tile + 2 * nW, iqn, jqn);

    float r0[4] = {0.f, 0.f, 0.f, 0.f};
    float r1[4] = {0.f, 0.f, 0.f, 0.f};
    const floatx4 zz = {0.f, 0.f, 0.f, 0.f};
#pragma unroll
    for (int h = 0; h < 2; h++) {  // hid col half: groups {h (Wa), 2+h (Wb)}
      floatx4 acc[4];
#pragma unroll
      for (int tt = 0; tt < 4; tt++) acc[tt] = zz;
      __builtin_amdgcn_s_setprio(1);
#pragma unroll
      for (int tt = 0; tt < 4; tt++) {
        acc[tt] = __builtin_amdgcn_mfma_f32_16x16x32_f16(
            I0, sBv[h * 512 + tt * 64 + lane], acc[tt], 0, 0, 0);
        acc[tt] = __builtin_amdgcn_mfma_f32_16x16x32_f16(
            I1, sBv[h * 512 + (4 + tt) * 64 + lane], acc[tt], 0, 0, 0);
        acc[tt] = __builtin_amdgcn_mfma_f32_16x16x32_f16(
            J0, sBv[(2 + h) * 512 + tt * 64 + lane], acc[tt], 0, 0, 0);
        acc[tt] = __builtin_amdgcn_mfma_f32_16x16x32_f16(
            J1, sBv[(2 + h) * 512 + (4 + tt) * 64 + lane], acc[tt], 0, 0, 0);
      }
      __builtin_amdgcn_s_setprio(0);
      // partial epilogue for this half: fold into persistent r0/r1
#pragma unroll
      for (int tt = 0; tt < 4; tt++) {
        int T = h * 4 + tt;  // hid col = T*16 + m_
#pragma unroll
        for (int rr = 0; rr < 4; rr++) {
          float hv = fmaxf(acc[tt][rr] + bb[T], 0.f);
          r0[rr] += hv * w0[T];
          r1[rr] += hv * w1[T];
        }
      }
      // pin half-1's MFMAs after half-0's fold: halves acc liveness (16 AGPR)
      __builtin_amdgcn_sched_barrier(0);
    }
    // reduce across the 16 lanes of each q-group and store
#pragma unroll
    for (int rr = 0; rr < 4; rr++) {
      float a0 = r0[rr], a1 = r1[rr];
#pragma unroll
      for (int off = 8; off > 0; off >>= 1) {
        a0 += __shfl_xor(a0, off, 16);
        a1 += __shfl_xor(a1, off, 16);
      }
      if (m_ == 0) {
        int q = tile * 16 + qk * 4 + rr;
        if (q < Q) {
          if (isb) {
            *reinterpret_cast<ushort2*>((unsigned short*)out + (size_t)q * 2) =
                make_ushort2(f2bf(a0 + ob0), f2bf(a1 + ob1));
          } else {
            *reinterpret_cast<float2*>((float*)out + (size_t)q * 2) =
                make_float2(a0 + ob0, a1 + ob1);
          }
        }
      }
    }
    // rotate pipeline buffers
    I0 = nI0; I1 = nI1; J0 = nJ0; J1 = nJ1;
  }
}

extern "C" void kernel_launch(void* const* d_in, const int* in_sizes, int n_in,
                              void* d_out, int out_size, void* d_ws, size_t ws_size,
                              hipStream_t stream) {
  const void* X    = d_in[0];
  const int*  edges= (const int*)d_in[1];
  const int*  qi   = (const int*)d_in[2];
  const int*  qj   = (const int*)d_in[3];
  const void* W1   = d_in[4];
  const void* b1   = d_in[5];
  const void* W2   = d_in[6];
  const void* b2   = d_in[7];
  const void* fc1W = d_in[8];
  const void* fc1b = d_in[9];
  const void* fc2W = d_in[10];
  const void* fc2b = d_in[11];

  const int N = in_sizes[0] / F_IN;
  const int E = in_sizes[1] / 2;
  const int Q = in_sizes[2];
  const int B = (N + NB - 1) / NB;           // buckets (<= MAXB for N <= 131072)
  const int chunk = (E + NWG - 1) / NWG;

  char* ws = (char*)d_ws;
  size_t off = 0;
  auto alloc = [&](size_t bytes) -> void* {
    void* p = ws + off;
    off += (bytes + 255) & ~(size_t)255;
    return p;
  };
  int*            flag = (int*)alloc(4);
  float*          dinv = (float*)alloc((size_t)N * 4);
  unsigned short* Xh   = (unsigned short*)alloc((size_t)N * F_IN * 2);   // fp16 X
  unsigned short* G    = (unsigned short*)alloc((size_t)N * F_HID * 2);  // gemm out (fp16)
  unsigned short* O    = (unsigned short*)alloc((size_t)N * F_HID * 2);  // layer out (fp16)
  unsigned short* fW1  = (unsigned short*)alloc((size_t)F_IN * F_HID * 2);   // frag-order fp16
  unsigned short* fW2  = (unsigned short*)alloc((size_t)F_HID * F_HID * 2);
  unsigned short* fPR  = (unsigned short*)alloc((size_t)4 * F_HID * 64 * 2);
  // bucket/CSR scratch
  int* hist = (int*)alloc((size_t)NWG * B * 4);
  int* btot = (int*)alloc((size_t)(B + 1) * 4);
  int* boff = (int*)alloc((size_t)(B + 1) * 4);
  int* buck = (int*)alloc((size_t)E * 4);
  int* csr  = (int*)alloc((size_t)E * 4);
  int* noff = (int*)alloc((size_t)(N + 1) * 4);
  (void)ws_size; (void)n_in; (void)out_size;

  const int* esrc = edges;
  const int* edst = edges + E;

  k_detect<<<1, 64, 0, stream>>>((const unsigned int*)X, flag);
  // fused xcast + weight prep + edge histogram (mutually independent)
  k_front<<<2048, 256, 0, stream>>>(X, Xh, N * F_IN / 8, W1, W2, fc1W, fW1, fW2, fPR,
                                    edst, hist, E, B, chunk, flag);

  // bucket scan + fill (bscan2 fused) + per-bucket counting sort -> CSR/dinv
  k_bscan1<<<(B + 3) / 4, 256, 0, stream>>>(hist, btot, B);
  k_bfill<<<NWG, 256, 0, stream>>>(esrc, edst, hist, btot, boff, buck, E, B, chunk);
  k_bsort<<<B, 256, 0, stream>>>(buck, boff, csr, noff, dinv, N);

  // layer 1
  k_gemm1<<<2048, 256, 0, stream>>>(Xh, fW1, dinv, G, N);
  k_agg<true><<<2048, 256, 0, stream>>>(csr, noff, G, dinv, b1, O, N, flag);

  // layer 2
  k_gemm2<<<2048, 256, 0, stream>>>(O, fW2, dinv, G, N);
  k_agg<false><<<2048, 256, 0, stream>>>(csr, noff, G, dinv, b2, O, N, flag);

  // per-query: gather O[i], O[j]; MFMA MLP on the fly (512-thread blocks)
  k_query<<<1024, 512, 0, stream>>>(O, fPR, qi, qj, fc1b, fc2W, fc2b, d_out, Q, flag);
}

// Round 15
// 407.601 us; speedup vs baseline: 1.1426x; 1.0113x over previous
//
#include <hip/hip_runtime.h>
#include <hip/hip_bf16.h>
#include <hip/hip_fp16.h>
#include <cstdint>

#define F_IN 128
#define F_HID 64
#define NB 64          // nodes per bucket
#define MAXB 2048      // max buckets (N <= 131072)
#define NWG 512        // WGs for hist/fill edge partition (2 blocks/CU in bfill)
#define PREPB 16       // prep blocks inside k_front
#define STAGE 6400     // k_bfill LDS staging capacity (63.4 KB total -> 2 blocks/CU)
#define SSTAGE 4096    // k_bsort LDS csr staging (buckets avg 2048 records)

typedef _Float16 half8 __attribute__((ext_vector_type(8)));
typedef float floatx4 __attribute__((ext_vector_type(4)));

__device__ __forceinline__ float bf2f(unsigned short u) {
  return __uint_as_float(((unsigned int)u) << 16);
}
__device__ __forceinline__ unsigned short f2bf(float f) {
  unsigned int u = __float_as_uint(f);
  u += 0x7FFFu + ((u >> 16) & 1u);   // round-to-nearest-even
  return (unsigned short)(u >> 16);
}
__device__ __forceinline__ float h2f(unsigned short u) {
  return __half2float(__ushort_as_half(u));
}
__device__ __forceinline__ unsigned short f2h(float f) {
  return __half_as_ushort(__float2half(f));
}

// ---------------- dtype detection kernel (round-12 lesson: do NOT inline —
// per-block redundant 256-word scans cost k_query +10us and k_agg +10us) ----
__global__ __launch_bounds__(64) void k_detect(const unsigned int* __restrict__ Xw,
                                               int* __restrict__ flag) {
  int lane = threadIdx.x;
  int cnt = 0;
  for (int t = lane; t < 256; t += 64) {
    unsigned int ex = (Xw[t] >> 7) & 0xFFu;
    cnt += (ex >= 117u && ex <= 137u) ? 1 : 0;
  }
#pragma unroll
  for (int off = 32; off > 0; off >>= 1) cnt += __shfl_xor(cnt, off, 64);
  if (lane == 0) *flag = (cnt >= 128) ? 1 : 0;  // 1 = bf16, 0 = fp32
}

// ---------------- fused front: bhist | weight-prep | xcast (independent) ----------------
// blocks [0,NWG): edge histogram; [NWG,NWG+PREPB): weight prep; rest: X cast.
__global__ __launch_bounds__(256) void k_front(const void* __restrict__ Xv,
                                               unsigned short* __restrict__ Xh, int total8,
                                               const void* __restrict__ W1v,
                                               const void* __restrict__ W2v,
                                               const void* __restrict__ fc1Wv,
                                               unsigned short* __restrict__ fW1,
                                               unsigned short* __restrict__ fW2,
                                               unsigned short* __restrict__ fPR,
                                               const int* __restrict__ dst,
                                               int* __restrict__ hist, int E, int B, int chunk,
                                               const int* __restrict__ flagp) {
  __shared__ int lh[MAXB];
  const int bid = blockIdx.x;
  if (bid < NWG) {  // ---- bhist ----
    int w = bid, tid = threadIdx.x;
    for (int b = tid; b < B; b += 256) lh[b] = 0;
    __syncthreads();
    int e0 = w * chunk, e1 = min(E, e0 + chunk);
    for (int e = e0 + tid; e < e1; e += 256) atomicAdd(&lh[dst[e] >> 6], 1);
    __syncthreads();
    for (int b = tid; b < B; b += 256) hist[w * B + b] = lh[b];
    return;
  }
  const bool isb = (*flagp != 0);
  if (bid < NWG + PREPB) {  // ---- weight prep (frag-order fp16) ----
    // B-frag for mfma_f32_16x16x32_f16: B[k=(lane>>4)*8+j][n=lane&15].
    // dest (ushorts) for W element (k,n): c=k>>5,q=(k>>3)&3,j=k&7,t=n>>4,m=n&15
    //   -> ((c*4+t)*64 + q*16+m)*8 + j
    int tid = (bid - NWG) * 256 + threadIdx.x;
    int stride = PREPB * 256;
    for (int e = tid; e < F_IN * F_HID; e += stride) {
      int k = e >> 6, n = e & 63;
      unsigned short v = isb ? f2h(bf2f(((const unsigned short*)W1v)[e]))
                             : f2h(((const float*)W1v)[e]);
      int c = k >> 5, q = (k >> 3) & 3, j = k & 7, t = n >> 4, m = n & 15;
      fW1[((c * 4 + t) * 64 + q * 16 + m) * 8 + j] = v;
    }
    for (int e = tid; e < F_HID * F_HID; e += stride) {
      int k = e >> 6, n = e & 63;
      unsigned short v = isb ? f2h(bf2f(((const unsigned short*)W2v)[e]))
                             : f2h(((const float*)W2v)[e]);
      int c = k >> 5, q = (k >> 3) & 3, j = k & 7, t = n >> 4, m = n & 15;
      fW2[((c * 4 + t) * 64 + q * 16 + m) * 8 + j] = v;
    }
    // fc1_W, 4 groups of 64x64: g&2 row half (Wa/Wb), g&1 col half
    for (int ge = tid; ge < 4 * F_HID * 64; ge += stride) {
      int g = ge >> 12, e = ge & 4095;
      int k = e >> 6, n = e & 63;
      int src = (((g & 2) ? 64 : 0) + k) * 128 + (g & 1) * 64 + n;
      unsigned short v = isb ? f2h(bf2f(((const unsigned short*)fc1Wv)[src]))
                             : f2h(((const float*)fc1Wv)[src]);
      int c = k >> 5, q = (k >> 3) & 3, j = k & 7, t = n >> 4, m = n & 15;
      fPR[g * 4096 + ((c * 4 + t) * 64 + q * 16 + m) * 8 + j] = v;
    }
    return;
  }
  // ---- xcast: lane-linear streaming bf16/fp32 -> fp16 ----
  int t = (bid - (NWG + PREPB)) * 256 + threadIdx.x;
  int stride = (gridDim.x - (NWG + PREPB)) * 256;
  for (; t < total8; t += stride) {
    unsigned short r[8];
    if (isb) {
      uint4 d = reinterpret_cast<const uint4*>(Xv)[t];  // 8 bf16
      r[0] = f2h(__uint_as_float(d.x << 16));
      r[1] = f2h(__uint_as_float(d.x & 0xFFFF0000u));
      r[2] = f2h(__uint_as_float(d.y << 16));
      r[3] = f2h(__uint_as_float(d.y & 0xFFFF0000u));
      r[4] = f2h(__uint_as_float(d.z << 16));
      r[5] = f2h(__uint_as_float(d.z & 0xFFFF0000u));
      r[6] = f2h(__uint_as_float(d.w << 16));
      r[7] = f2h(__uint_as_float(d.w & 0xFFFF0000u));
    } else {
      float4 a = reinterpret_cast<const float4*>(Xv)[2 * t];
      float4 b = reinterpret_cast<const float4*>(Xv)[2 * t + 1];
      r[0] = f2h(a.x); r[1] = f2h(a.y); r[2] = f2h(a.z); r[3] = f2h(a.w);
      r[4] = f2h(b.x); r[5] = f2h(b.y); r[6] = f2h(b.z); r[7] = f2h(b.w);
    }
    uint4 o;
    o.x = (unsigned int)r[0] | ((unsigned int)r[1] << 16);
    o.y = (unsigned int)r[2] | ((unsigned int)r[3] << 16);
    o.z = (unsigned int)r[4] | ((unsigned int)r[5] << 16);
    o.w = (unsigned int)r[6] | ((unsigned int)r[7] << 16);
    reinterpret_cast<uint4*>(Xh)[t] = o;
  }
}

// ---------------- bscan1: wave-per-bucket parallel scan over W=NWG ----------------
__global__ __launch_bounds__(256) void k_bscan1(int* __restrict__ hist,
                                                int* __restrict__ btot, int B) {
  const int WPL = NWG / 64;  // hist entries per lane
  int b = (blockIdx.x * 256 + threadIdx.x) >> 6;  // bucket = global wave id
  int lane = threadIdx.x & 63;
  if (b >= B) return;
  int v[WPL];
  int s = 0;
#pragma unroll
  for (int k = 0; k < WPL; k++) {
    v[k] = hist[(size_t)(lane * WPL + k) * B + b];
    s += v[k];
  }
  // inclusive scan of s across 64 lanes -> exclusive prefix
  int pre = s;
#pragma unroll
  for (int off = 1; off < 64; off <<= 1) {
    int t = __shfl_up(pre, off, 64);
    if (lane >= off) pre += t;
  }
  int running = pre - s;  // exclusive
#pragma unroll
  for (int k = 0; k < WPL; k++) {
    int val = v[k];
    hist[(size_t)(lane * WPL + k) * B + b] = running;
    running += val;
  }
  if (lane == 63) btot[b] = running;  // bucket total
}

// ---------------- bfill: LDS-staged counting sort + fused bucket-base scan ----------------
// bscan2 fused: each block computes boff locally from btot; block 0 publishes
// global boff for k_bsort. LDS-staged binning: write p-linearly so consecutive
// lanes write consecutive buck[] slots. STAGE=6400 keeps LDS at ~63 KB so
// 2 blocks/CU fit. record = (dst_local << 17) | src (needs N <= 131072).
__global__ __launch_bounds__(256) void k_bfill(const int* __restrict__ src,
                                               const int* __restrict__ dst,
                                               const int* __restrict__ hist,
                                               const int* __restrict__ btot,
                                               int* __restrict__ boff,
                                               int* __restrict__ buck,
                                               int E, int B, int chunk) {
  __shared__ int gcur[MAXB];                 // global write base per bucket
  __shared__ int lexcl[MAXB];                // local excl offsets (temp: boff)
  __shared__ int lcur[MAXB];                 // placement cursors
  __shared__ int stage[STAGE];               // bucket-sorted records
  __shared__ unsigned short bdex[STAGE];     // bucket id per staged slot
  __shared__ int part[256];
  const int w = blockIdx.x, tid = threadIdx.x;
  // ---- fused bscan2: local exclusive scan of btot -> bucket bases ----
  {
    int CH = (B + 255) >> 8;
    int b0 = tid * CH, b1 = min(B, b0 + CH);
    int s = 0;
    for (int b = b0; b < b1; b++) s += btot[b];
    part[tid] = s;
    __syncthreads();
    if (tid == 0) {
      int acc = 0;
      for (int i = 0; i < 256; i++) { int v = part[i]; part[i] = acc; acc += v; }
    }
    __syncthreads();
    int run = part[tid];
    for (int b = b0; b < b1; b++) { lexcl[b] = run; run += btot[b]; }
    __syncthreads();
    for (int b = tid; b < B; b += 256) gcur[b] = lexcl[b] + hist[w * B + b];
    if (w == 0) {  // publish for k_bsort
      for (int b = tid; b < B; b += 256) boff[b] = lexcl[b];
      if (tid == 0) boff[B] = E;
    }
    __syncthreads();  // lexcl free for reuse below
  }
  int e0 = w * chunk, e1 = min(E, e0 + chunk);
  for (int s0 = e0; s0 < e1; s0 += STAGE) {
    int s1 = min(e1, s0 + STAGE);
    int cnt = s1 - s0;
    for (int b = tid; b < B; b += 256) lexcl[b] = 0;
    __syncthreads();
    for (int e = s0 + tid; e < s1; e += 256) atomicAdd(&lexcl[dst[e] >> 6], 1);
    __syncthreads();
    // block exclusive scan of lexcl; init lcur
    int CH = (B + 255) >> 8;
    int b0 = tid * CH, b1 = min(B, b0 + CH);
    int s = 0;
    for (int b = b0; b < b1; b++) s += lexcl[b];
    part[tid] = s;
    __syncthreads();
    if (tid == 0) {
      int acc = 0;
      for (int i = 0; i < 256; i++) { int v = part[i]; part[i] = acc; acc += v; }
    }
    __syncthreads();
    int run = part[tid];
    for (int b = b0; b < b1; b++) {
      int v = lexcl[b];
      lexcl[b] = run;
      lcur[b] = run;
      run += v;
    }
    __syncthreads();
    // place records bucket-sorted into stage
    for (int e = s0 + tid; e < s1; e += 256) {
      int d = dst[e];
      int b = d >> 6;
      int p = atomicAdd(&lcur[b], 1);
      stage[p] = ((d & 63) << 17) | src[e];
      bdex[p] = (unsigned short)b;
    }
    __syncthreads();
    // p-linear write-out: consecutive p -> consecutive dest within runs
    for (int p = tid; p < cnt; p += 256) {
      int b = bdex[p];
      buck[gcur[b] + (p - lexcl[b])] = stage[p];
    }
    __syncthreads();
    // advance global bases by this sub-chunk's per-bucket counts
    for (int b = tid; b < B; b += 256) gcur[b] += lcur[b] - lexcl[b];
    __syncthreads();
  }
}

// ---------------- per-bucket counting sort -> exact per-node CSR ----------------
// 8-way replicated counters/cursors (bin[dl][rep], rep = tid&7) cut atomic
// serialization. NEW (round-15): csr written via 16 KB LDS stage then linear
// store — the old direct scatter placed each 4 B at a random slot in the
// bucket's ~8 KB segment (~8x write amplification, the round-6 bfill disease).
// Overflow guard: buckets > SSTAGE records use the legacy scatter path.
__global__ __launch_bounds__(256) void k_bsort(const int* __restrict__ buck,
                                               const int* __restrict__ boff,
                                               int* __restrict__ csr,
                                               int* __restrict__ noff,
                                               float* __restrict__ dinv, int N) {
  __shared__ int bin[NB][8];
  __shared__ int excl[NB];
  __shared__ int sstage[SSTAGE];
  int b = blockIdx.x, tid = threadIdx.x;
  const int rep = tid & 7;
  for (int i = tid; i < NB * 8; i += 256) ((int*)bin)[i] = 0;
  __syncthreads();
  int r0 = boff[b], r1 = boff[b + 1];
  for (int r = r0 + tid; r < r1; r += 256) atomicAdd(&bin[buck[r] >> 17][rep], 1);
  __syncthreads();
  if (tid < NB) {
    int t = 0;
#pragma unroll
    for (int r = 0; r < 8; r++) t += bin[tid][r];
    excl[tid] = t;
  }
  __syncthreads();
  if (tid == 0) {
    int acc = 0;
    for (int i = 0; i < NB; i++) { int v = excl[i]; excl[i] = acc; acc += v; }
  }
  __syncthreads();
  if (tid < NB) {
    int n = b * NB + tid;
    int tot = 0;
#pragma unroll
    for (int r = 0; r < 8; r++) tot += bin[tid][r];
    if (n < N) {
      dinv[n] = rsqrtf((float)tot + 1.0f);  // +1 self-loop
      noff[n] = r0 + excl[tid];
    }
    // replica cursors: disjoint sub-ranges of this node's segment
    int acc = excl[tid];
#pragma unroll
    for (int r = 0; r < 8; r++) { int c = bin[tid][r]; bin[tid][r] = acc; acc += c; }
  }
  if (b == gridDim.x - 1 && tid == 128) noff[N] = r1;  // r1 == E for last bucket
  __syncthreads();
  int cnt = r1 - r0;
  if (cnt <= SSTAGE) {
    // LDS-staged: place into sstage, then linear coalesced csr write
    for (int r = r0 + tid; r < r1; r += 256) {
      int rec = buck[r];
      int p = atomicAdd(&bin[rec >> 17][rep], 1);
      sstage[p] = rec & 0x1FFFF;
    }
    __syncthreads();
    for (int p = tid; p < cnt; p += 256) csr[r0 + p] = sstage[p];
  } else {
    // oversize bucket fallback: direct scatter (correct for any distribution)
    for (int r = r0 + tid; r < r1; r += 256) {
      int rec = buck[r];
      int p = atomicAdd(&bin[rec >> 17][rep], 1);
      csr[r0 + p] = rec & 0x1FFFF;
    }
  }
}

// ============ MFMA GEMMs (mfma_f32_16x16x32_f16), all inputs fp16 ============
// A-frag:  A[m = lane&15][k = (lane>>4)*8 + j]
// D:       D[row = (lane>>4)*4 + reg][col = lane&15]

// ---------------- GEMM1: G = fp16((Xh @ W1) * dinv[row])   (Xh fp16 N x 128) ----------------
__global__ __launch_bounds__(256, 4) void k_gemm1(const unsigned short* __restrict__ Xh,
                                                  const unsigned short* __restrict__ fW1,
                                                  const float* __restrict__ dinv,
                                                  unsigned short* __restrict__ G, int N) {
  int tid = threadIdx.x;
  const int lane = tid & 63, wave = tid >> 6;
  const int m = lane & 15, q = lane >> 4;
  half8 bfrag[4][4];
#pragma unroll
  for (int c = 0; c < 4; c++)
#pragma unroll
    for (int t = 0; t < 4; t++)
      bfrag[c][t] = *reinterpret_cast<const half8*>(fW1 + ((c * 4 + t) * 64 + lane) * 8);
  int ntiles = (N + 15) >> 4;
  for (int tile = blockIdx.x * 4 + wave; tile < ntiles; tile += gridDim.x * 4) {
    int r0 = tile << 4;
    int rm = r0 + m; rm = rm < N ? rm : N - 1;
    floatx4 acc[4] = {{0.f,0.f,0.f,0.f},{0.f,0.f,0.f,0.f},{0.f,0.f,0.f,0.f},{0.f,0.f,0.f,0.f}};
#pragma unroll
    for (int c = 0; c < 4; c++) {
      half8 a = *reinterpret_cast<const half8*>(Xh + (size_t)rm * F_IN + c * 32 + q * 8);
#pragma unroll
      for (int t = 0; t < 4; t++)
        acc[t] = __builtin_amdgcn_mfma_f32_16x16x32_f16(a, bfrag[c][t], acc[t], 0, 0, 0);
    }
#pragma unroll
    for (int rr = 0; rr < 4; rr++) {
      int grow = r0 + q * 4 + rr;
      if (grow < N) {
        float dv = dinv[grow];
#pragma unroll
        for (int t = 0; t < 4; t++)
          G[(size_t)grow * F_HID + t * 16 + m] = f2h(acc[t][rr] * dv);
      }
    }
  }
}

// ---------------- GEMM2: G = fp16((O @ W2) * dinv[row])   (O fp16) ----------------
__global__ __launch_bounds__(256, 4) void k_gemm2(const unsigned short* __restrict__ O,
                                                  const unsigned short* __restrict__ fW2,
                                                  const float* __restrict__ dinv,
                                                  unsigned short* __restrict__ G, int N) {
  int tid = threadIdx.x;
  const int lane = tid & 63, wave = tid >> 6;
  const int m = lane & 15, q = lane >> 4;
  half8 bfrag[2][4];
#pragma unroll
  for (int c = 0; c < 2; c++)
#pragma unroll
    for (int t = 0; t < 4; t++)
      bfrag[c][t] = *reinterpret_cast<const half8*>(fW2 + ((c * 4 + t) * 64 + lane) * 8);
  int ntiles = (N + 15) >> 4;
  for (int tile = blockIdx.x * 4 + wave; tile < ntiles; tile += gridDim.x * 4) {
    int r0 = tile << 4;
    int rm = r0 + m; rm = rm < N ? rm : N - 1;
    floatx4 acc[4] = {{0.f,0.f,0.f,0.f},{0.f,0.f,0.f,0.f},{0.f,0.f,0.f,0.f},{0.f,0.f,0.f,0.f}};
#pragma unroll
    for (int c = 0; c < 2; c++) {
      half8 a = *reinterpret_cast<const half8*>(O + (size_t)rm * F_HID + c * 32 + q * 8);
#pragma unroll
      for (int t = 0; t < 4; t++)
        acc[t] = __builtin_amdgcn_mfma_f32_16x16x32_f16(a, bfrag[c][t], acc[t], 0, 0, 0);
    }
#pragma unroll
    for (int rr = 0; rr < 4; rr++) {
      int grow = r0 + q * 4 + rr;
      if (grow < N) {
        float dv = dinv[grow];
#pragma unroll
        for (int t = 0; t < 4; t++)
          G[(size_t)grow * F_HID + t * 16 + m] = f2h(acc[t][rr] * dv);
      }
    }
  }
}

// ---------------- aggregate: 4 rows/instruction group-gather + fused epilogue ----------------
template <bool RELU>
__global__ __launch_bounds__(256) void k_agg(const int* __restrict__ csr,
                                             const int* __restrict__ noff,
                                             const unsigned short* __restrict__ H,
                                             const float* __restrict__ dinv,
                                             const void* __restrict__ bias,
                                             unsigned short* __restrict__ OUT, int N,
                                             const int* __restrict__ flagp) {
  const bool isb = (*flagp != 0);
  const int lane = threadIdx.x & 63;
  const int g = lane >> 4, l16 = lane & 15;
  const int gw = (blockIdx.x * 256 + threadIdx.x) >> 6;
  const int nW = (gridDim.x * 256) >> 6;
  float bv[4];
#pragma unroll
  for (int d = 0; d < 4; d++)
    bv[d] = isb ? bf2f(((const unsigned short*)bias)[l16 * 4 + d])
                : ((const float*)bias)[l16 * 4 + d];
  for (int n = gw; n < N; n += nW) {
    int start = noff[n], end = noff[n + 1];
    float a0 = 0.f, a1 = 0.f, a2 = 0.f, a3 = 0.f;
    for (int e0 = start; e0 < end; e0 += 64) {
      int ee = e0 + lane;
      int idx = (ee < end) ? csr[ee] : 0;
      int m = end - e0; m = m < 64 ? m : 64;
      int nc = m >> 2;  // full 4-row chunks
      int c = 0;
      for (; c + 8 <= nc; c += 8) {  // 32 rows in flight
        int s[8];
#pragma unroll
        for (int u = 0; u < 8; u++) s[u] = __shfl(idx, (c + u) * 4 + g, 64);
        ushort4 v[8];
#pragma unroll
        for (int u = 0; u < 8; u++)
          v[u] = *reinterpret_cast<const ushort4*>(H + (size_t)s[u] * F_HID + l16 * 4);
#pragma unroll
        for (int u = 0; u < 8; u++) {
          a0 += h2f(v[u].x); a1 += h2f(v[u].y);
          a2 += h2f(v[u].z); a3 += h2f(v[u].w);
        }
      }
      for (; c < nc; c++) {
        int s0 = __shfl(idx, c * 4 + g, 64);
        ushort4 v0 = *reinterpret_cast<const ushort4*>(H + (size_t)s0 * F_HID + l16 * 4);
        a0 += h2f(v0.x); a1 += h2f(v0.y); a2 += h2f(v0.z); a3 += h2f(v0.w);
      }
      int rem = m & 3;
      if (rem) {
        int s0 = __shfl(idx, nc * 4 + g, 64);  // shfl outside divergence
        if (g < rem) {
          ushort4 v0 = *reinterpret_cast<const ushort4*>(H + (size_t)s0 * F_HID + l16 * 4);
          a0 += h2f(v0.x); a1 += h2f(v0.y); a2 += h2f(v0.z); a3 += h2f(v0.w);
        }
      }
    }
    // cross-group reduce (butterfly: all lanes end with totals)
    a0 += __shfl_xor(a0, 16, 64); a0 += __shfl_xor(a0, 32, 64);
    a1 += __shfl_xor(a1, 16, 64); a1 += __shfl_xor(a1, 32, 64);
    a2 += __shfl_xor(a2, 16, 64); a2 += __shfl_xor(a2, 32, 64);
    a3 += __shfl_xor(a3, 16, 64); a3 += __shfl_xor(a3, 32, 64);
    // self-loop + scale + bias (+relu), vector store by lanes 0-15
    ushort4 sv = *reinterpret_cast<const ushort4*>(H + (size_t)n * F_HID + l16 * 4);
    float dv = dinv[n];
    float o0 = (a0 + h2f(sv.x)) * dv + bv[0];
    float o1 = (a1 + h2f(sv.y)) * dv + bv[1];
    float o2 = (a2 + h2f(sv.z)) * dv + bv[2];
    float o3 = (a3 + h2f(sv.w)) * dv + bv[3];
    if (RELU) {
      o0 = fmaxf(o0, 0.f); o1 = fmaxf(o1, 0.f);
      o2 = fmaxf(o2, 0.f); o3 = fmaxf(o3, 0.f);
    }
    if (lane < 16) {
      ushort4 ov;
      ov.x = f2h(o0); ov.y = f2h(o1); ov.z = f2h(o2); ov.w = f2h(o3);
      *reinterpret_cast<ushort4*>(OUT + (size_t)n * F_HID + l16 * 4) = ov;
    }
  }
}

// ---------------- query: gather O[i], O[j]; on-the-fly MFMA MLP ----------------
// out[q] = relu(O[i]@Wa + O[j]@Wb + fc1_b) @ fc2_W + fc2_b
// 512-thread blocks (8 waves share the 32 KB weight copy), depth-1 pipelined
// gathers, sched_barrier acc-halving, setprio around MFMA. ~69 us — pinned at
// the L2/L3 random-line service rate (rounds 8-10 all plateau here).
__global__ __launch_bounds__(512) void k_query(const unsigned short* __restrict__ O,
                                               const unsigned short* __restrict__ fPR,
                                               const int* __restrict__ qi,
                                               const int* __restrict__ qj,
                                               const void* __restrict__ fc1b,
                                               const void* __restrict__ fc2W,
                                               const void* __restrict__ fc2b,
                                               void* __restrict__ out, int Q,
                                               const int* __restrict__ flagp) {
  __shared__ unsigned short sB[4 * 4096];  // 32 KB: fc1_W frag-order
  const bool isb = (*flagp != 0);
  int tid = threadIdx.x;
  {
    const uint4* srcp = reinterpret_cast<const uint4*>(fPR);
    uint4* dstp = reinterpret_cast<uint4*>(sB);
#pragma unroll
    for (int r = 0; r < 4; r++) dstp[tid + r * 512] = srcp[tid + r * 512];
  }
  const int lane = tid & 63, wave = tid >> 6;  // wave in [0,8)
  const int m_ = lane & 15, qk = lane >> 4;
  // per-lane epilogue LUT for hid cols h = T*16 + m_
  float bb[8], w0[8], w1[8];
#pragma unroll
  for (int T = 0; T < 8; T++) {
    int h = T * 16 + m_;
    if (isb) {
      bb[T] = bf2f(((const unsigned short*)fc1b)[h]);
      w0[T] = bf2f(((const unsigned short*)fc2W)[h * 2 + 0]);
      w1[T] = bf2f(((const unsigned short*)fc2W)[h * 2 + 1]);
    } else {
      bb[T] = ((const float*)fc1b)[h];
      w0[T] = ((const float*)fc2W)[h * 2 + 0];
      w1[T] = ((const float*)fc2W)[h * 2 + 1];
    }
  }
  float ob0 = isb ? bf2f(((const unsigned short*)fc2b)[0]) : ((const float*)fc2b)[0];
  float ob1 = isb ? bf2f(((const unsigned short*)fc2b)[1]) : ((const float*)fc2b)[1];
  __syncthreads();
  const half8* sBv = reinterpret_cast<const half8*>(sB);  // group stride 512 half8

  const int ntiles = (Q + 15) >> 4;
  const int nW = gridDim.x * 8;
  int tile = blockIdx.x * 8 + wave;
  if (tile >= ntiles) return;

  auto ldidx = [&](int t, int& iq, int& jq) {
    if (t < ntiles) {
      int q = t * 16 + m_;
      int qq = q < Q ? q : Q - 1;
      iq = qi[qq];
      jq = qj[qq];
    }  // else keep previous (harmless row re-gather)
  };
  auto gather = [&](int iq, int jq, half8& I0, half8& I1, half8& J0, half8& J1) {
    const half8* pI = reinterpret_cast<const half8*>(O + (size_t)iq * F_HID) + qk;
    const half8* pJ = reinterpret_cast<const half8*>(O + (size_t)jq * F_HID) + qk;
    I0 = pI[0]; I1 = pI[4];  // k 0-31 / 32-63
    J0 = pJ[0]; J1 = pJ[4];
  };

  // pipeline prologue: idx(t), rows(t), idx(t+1)
  int iqn = 0, jqn = 0;
  ldidx(tile, iqn, jqn);
  half8 I0, I1, J0, J1;
  gather(iqn, jqn, I0, I1, J0, J1);
  ldidx(tile + nW, iqn, jqn);

  for (; tile < ntiles; tile += nW) {
    // issue NEXT tile's row gathers + the tile after's index loads first;
    // they drain while we compute the current tile.
    half8 nI0, nI1, nJ0, nJ1;
    gather(iqn, jqn, nI0, nI1, nJ0, nJ1);
    ldidx(tile + 2 * nW, iqn, jqn);

    float r0[4] = {0.f, 0.f, 0.f, 0.f};
    float r1[4] = {0.f, 0.f, 0.f, 0.f};
    const floatx4 zz = {0.f, 0.f, 0.f, 0.f};
#pragma unroll
    for (int h = 0; h < 2; h++) {  // hid col half: groups {h (Wa), 2+h (Wb)}
      floatx4 acc[4];
#pragma unroll
      for (int tt = 0; tt < 4; tt++) acc[tt] = zz;
      __builtin_amdgcn_s_setprio(1);
#pragma unroll
      for (int tt = 0; tt < 4; tt++) {
        acc[tt] = __builtin_amdgcn_mfma_f32_16x16x32_f16(
            I0, sBv[h * 512 + tt * 64 + lane], acc[tt], 0, 0, 0);
        acc[tt] = __builtin_amdgcn_mfma_f32_16x16x32_f16(
            I1, sBv[h * 512 + (4 + tt) * 64 + lane], acc[tt], 0, 0, 0);
        acc[tt] = __builtin_amdgcn_mfma_f32_16x16x32_f16(
            J0, sBv[(2 + h) * 512 + tt * 64 + lane], acc[tt], 0, 0, 0);
        acc[tt] = __builtin_amdgcn_mfma_f32_16x16x32_f16(
            J1, sBv[(2 + h) * 512 + (4 + tt) * 64 + lane], acc[tt], 0, 0, 0);
      }
      __builtin_amdgcn_s_setprio(0);
      // partial epilogue for this half: fold into persistent r0/r1
#pragma unroll
      for (int tt = 0; tt < 4; tt++) {
        int T = h * 4 + tt;  // hid col = T*16 + m_
#pragma unroll
        for (int rr = 0; rr < 4; rr++) {
          float hv = fmaxf(acc[tt][rr] + bb[T], 0.f);
          r0[rr] += hv * w0[T];
          r1[rr] += hv * w1[T];
        }
      }
      // pin half-1's MFMAs after half-0's fold: halves acc liveness (16 AGPR)
      __builtin_amdgcn_sched_barrier(0);
    }
    // reduce across the 16 lanes of each q-group and store
#pragma unroll
    for (int rr = 0; rr < 4; rr++) {
      float a0 = r0[rr], a1 = r1[rr];
#pragma unroll
      for (int off = 8; off > 0; off >>= 1) {
        a0 += __shfl_xor(a0, off, 16);
        a1 += __shfl_xor(a1, off, 16);
      }
      if (m_ == 0) {
        int q = tile * 16 + qk * 4 + rr;
        if (q < Q) {
          if (isb) {
            *reinterpret_cast<ushort2*>((unsigned short*)out + (size_t)q * 2) =
                make_ushort2(f2bf(a0 + ob0), f2bf(a1 + ob1));
          } else {
            *reinterpret_cast<float2*>((float*)out + (size_t)q * 2) =
                make_float2(a0 + ob0, a1 + ob1);
          }
        }
      }
    }
    // rotate pipeline buffers
    I0 = nI0; I1 = nI1; J0 = nJ0; J1 = nJ1;
  }
}

extern "C" void kernel_launch(void* const* d_in, const int* in_sizes, int n_in,
                              void* d_out, int out_size, void* d_ws, size_t ws_size,
                              hipStream_t stream) {
  const void* X    = d_in[0];
  const int*  edges= (const int*)d_in[1];
  const int*  qi   = (const int*)d_in[2];
  const int*  qj   = (const int*)d_in[3];
  const void* W1   = d_in[4];
  const void* b1   = d_in[5];
  const void* W2   = d_in[6];
  const void* b2   = d_in[7];
  const void* fc1W = d_in[8];
  const void* fc1b = d_in[9];
  const void* fc2W = d_in[10];
  const void* fc2b = d_in[11];

  const int N = in_sizes[0] / F_IN;
  const int E = in_sizes[1] / 2;
  const int Q = in_sizes[2];
  const int B = (N + NB - 1) / NB;           // buckets (<= MAXB for N <= 131072)
  const int chunk = (E + NWG - 1) / NWG;

  char* ws = (char*)d_ws;
  size_t off = 0;
  auto alloc = [&](size_t bytes) -> void* {
    void* p = ws + off;
    off += (bytes + 255) & ~(size_t)255;
    return p;
  };
  int*            flag = (int*)alloc(4);
  float*          dinv = (float*)alloc((size_t)N * 4);
  unsigned short* Xh   = (unsigned short*)alloc((size_t)N * F_IN * 2);   // fp16 X
  unsigned short* G    = (unsigned short*)alloc((size_t)N * F_HID * 2);  // gemm out (fp16)
  unsigned short* O    = (unsigned short*)alloc((size_t)N * F_HID * 2);  // layer out (fp16)
  unsigned short* fW1  = (unsigned short*)alloc((size_t)F_IN * F_HID * 2);   // frag-order fp16
  unsigned short* fW2  = (unsigned short*)alloc((size_t)F_HID * F_HID * 2);
  unsigned short* fPR  = (unsigned short*)alloc((size_t)4 * F_HID * 64 * 2);
  // bucket/CSR scratch
  int* hist = (int*)alloc((size_t)NWG * B * 4);
  int* btot = (int*)alloc((size_t)(B + 1) * 4);
  int* boff = (int*)alloc((size_t)(B + 1) * 4);
  int* buck = (int*)alloc((size_t)E * 4);
  int* csr  = (int*)alloc((size_t)E * 4);
  int* noff = (int*)alloc((size_t)(N + 1) * 4);
  (void)ws_size; (void)n_in; (void)out_size;

  const int* esrc = edges;
  const int* edst = edges + E;

  k_detect<<<1, 64, 0, stream>>>((const unsigned int*)X, flag);
  // fused xcast + weight prep + edge histogram (mutually independent)
  k_front<<<2048, 256, 0, stream>>>(X, Xh, N * F_IN / 8, W1, W2, fc1W, fW1, fW2, fPR,
                                    edst, hist, E, B, chunk, flag);

  // bucket scan + fill (bscan2 fused) + per-bucket counting sort -> CSR/dinv
  k_bscan1<<<(B + 3) / 4, 256, 0, stream>>>(hist, btot, B);
  k_bfill<<<NWG, 256, 0, stream>>>(esrc, edst, hist, btot, boff, buck, E, B, chunk);
  k_bsort<<<B, 256, 0, stream>>>(buck, boff, csr, noff, dinv, N);

  // layer 1
  k_gemm1<<<2048, 256, 0, stream>>>(Xh, fW1, dinv, G, N);
  k_agg<true><<<2048, 256, 0, stream>>>(csr, noff, G, dinv, b1, O, N, flag);

  // layer 2
  k_gemm2<<<2048, 256, 0, stream>>>(O, fW2, dinv, G, N);
  k_agg<false><<<2048, 256, 0, stream>>>(csr, noff, G, dinv, b2, O, N, flag);

  // per-query: gather O[i], O[j]; MFMA MLP on the fly (512-thread blocks)
  k_query<<<1024, 512, 0, stream>>>(O, fPR, qi, qj, fc1b, fc2W, fc2b, d_out, Q, flag);
}